// Round 1
// baseline (1137.193 us; speedup 1.0000x reference)
//
#include <hip/hip_runtime.h>
#include <math.h>

// Problem constants
#define EMBED   128
#define DMODEL  256   // 2*EMBED
#define DINNER  512
#define HIDN    512
#define NBK     200
#define BQ      1024
#define FEW     5
#define PAD_IDX 200000
#define LN_EPS  1e-5f

__device__ __forceinline__ float sigmoidf_(float x) { return 1.0f / (1.0f + expf(-x)); }

// ---------------------------------------------------------------------------
// Kernel 1: neighbor encoder.
// Blocks 0..1023: query_left -> qn[n, 0:128]; 1024..2047: query_right -> qn[n,128:256]
// 2048..2052: support_left -> sn[n,0:128];   2053..2057: support_right -> sn[n,128:256]
// Each block: 256 threads. Thread t: wave w=t/64, lane l=t&63; d = w*32+(l&31),
// half = l>>5. W[d, half*128 .. +127] held in 32 float4 registers (reused over k).
// x (emb[rel]||emb[ent], 256 floats) staged in LDS per k; half-dot per lane,
// combined across half-waves via shfl_xor(32).
// ---------------------------------------------------------------------------
__global__ __launch_bounds__(256) void neighbor_kernel(
    const int* __restrict__ qlc, const int* __restrict__ qrc,
    const int* __restrict__ slc, const int* __restrict__ src_,
    const float* __restrict__ emb, const float* __restrict__ W,
    const float* __restrict__ wb,  const float* __restrict__ bb,
    float* __restrict__ qn, float* __restrict__ sn)
{
    int b = blockIdx.x;
    const int* conn; float* out; int n; int side;
    if (b < BQ)                { conn = qlc;  n = b;            side = 0; out = qn; }
    else if (b < 2*BQ)         { conn = qrc;  n = b - BQ;       side = 1; out = qn; }
    else if (b < 2*BQ + FEW)   { conn = slc;  n = b - 2*BQ;     side = 0; out = sn; }
    else                       { conn = src_; n = b - 2*BQ-FEW; side = 1; out = sn; }

    int t = threadIdx.x;
    int w = t >> 6, l = t & 63;
    int d = w * 32 + (l & 31);
    int half = l >> 5;

    // Load my W row-half into registers (128 floats = 32 float4)
    float4 wreg[32];
    const float4* wsrc = (const float4*)(W + d * DMODEL + half * EMBED);
    #pragma unroll
    for (int j = 0; j < 32; ++j) wreg[j] = wsrc[j];

    float bias = wb[d] + bb[d];

    __shared__ __align__(16) float xs[DMODEL];
    float m = -INFINITY;
    const int* crow = conn + n * NBK * 2;
    int sel_ent = (t >= EMBED);          // threads 128..255 load ent row
    int j0 = t & (EMBED - 1);

    for (int k = 0; k < NBK; ++k) {
        int rel = crow[2 * k + 0];
        int ent = crow[2 * k + 1];
        if (rel == PAD_IDX || ent == PAD_IDX) continue;  // uniform across block
        int row = sel_ent ? ent : rel;
        xs[t] = emb[row * EMBED + j0];
        __syncthreads();
        const float4* xp = (const float4*)(xs + half * EMBED);
        float acc = 0.f;
        #pragma unroll
        for (int j4 = 0; j4 < 32; ++j4) {
            float4 xv = xp[j4];
            float4 wv = wreg[j4];
            acc += wv.x * xv.x + wv.y * xv.y + wv.z * xv.z + wv.w * xv.w;
        }
        float other = __shfl_xor(acc, 32, 64);
        float p = acc + other + bias;
        p = (p >= 0.f) ? p : 0.1f * p;   // leaky_relu(0.1)
        m = fmaxf(m, p);
        __syncthreads();
    }
    if (half == 0) out[n * DMODEL + side * EMBED + d] = tanhf(m);
}

// ---------------------------------------------------------------------------
// Kernel 2: support encoder (MLP + residual + LN) for 1029 rows
// (1024 query rows from qn, 5 support rows from sn). 8 rows per block.
// ---------------------------------------------------------------------------
#define SE_ROWS 8
__global__ __launch_bounds__(256) void support_enc_kernel(
    const float* __restrict__ qn, const float* __restrict__ sn,
    const float* __restrict__ p1W, const float* __restrict__ p1b,
    const float* __restrict__ p2W, const float* __restrict__ p2b,
    const float* __restrict__ lng, const float* __restrict__ lnb,
    float* __restrict__ query_g, float* __restrict__ sup_ln)
{
    __shared__ __align__(16) float xs[SE_ROWS][DMODEL];
    __shared__ __align__(16) float hs[SE_ROWS][DINNER];
    __shared__ __align__(16) float os[SE_ROWS][DMODEL];
    int t = threadIdx.x;
    int base_row = blockIdx.x * SE_ROWS;

    for (int r = 0; r < SE_ROWS; ++r) {
        int row = base_row + r;
        float v = 0.f;
        if (row < BQ + FEW)
            v = (row < BQ) ? qn[row * DMODEL + t] : sn[(row - BQ) * DMODEL + t];
        xs[r][t] = v;
    }
    __syncthreads();

    // h = relu(x @ p1W.T + p1b): each thread does j = t and t+256
    for (int jj = 0; jj < 2; ++jj) {
        int j = t + jj * 256;
        const float4* wrow = (const float4*)(p1W + j * DMODEL);
        float acc[SE_ROWS];
        #pragma unroll
        for (int r = 0; r < SE_ROWS; ++r) acc[r] = 0.f;
        for (int e = 0; e < DMODEL / 4; ++e) {
            float4 wv = wrow[e];
            #pragma unroll
            for (int r = 0; r < SE_ROWS; ++r) {
                float4 xv = ((const float4*)xs[r])[e];
                acc[r] += wv.x * xv.x + wv.y * xv.y + wv.z * xv.z + wv.w * xv.w;
            }
        }
        float bj = p1b[j];
        #pragma unroll
        for (int r = 0; r < SE_ROWS; ++r) hs[r][j] = fmaxf(acc[r] + bj, 0.f);
    }
    __syncthreads();

    // o = h @ p2W.T + p2b + x
    {
        const float4* wrow = (const float4*)(p2W + t * DINNER);
        float acc[SE_ROWS];
        #pragma unroll
        for (int r = 0; r < SE_ROWS; ++r) acc[r] = 0.f;
        for (int e = 0; e < DINNER / 4; ++e) {
            float4 wv = wrow[e];
            #pragma unroll
            for (int r = 0; r < SE_ROWS; ++r) {
                float4 hv = ((const float4*)hs[r])[e];
                acc[r] += wv.x * hv.x + wv.y * hv.y + wv.z * hv.z + wv.w * hv.w;
            }
        }
        float bt = p2b[t];
        #pragma unroll
        for (int r = 0; r < SE_ROWS; ++r) os[r][t] = acc[r] + bt + xs[r][t];
    }
    __syncthreads();

    // LayerNorm per row: wave w handles rows 2w, 2w+1
    int w = t >> 6, l = t & 63;
    for (int rr = 0; rr < 2; ++rr) {
        int r = w * 2 + rr;
        float sum = 0.f, sq = 0.f;
        for (int i = 0; i < 4; ++i) {
            float v = os[r][l + 64 * i];
            sum += v; sq += v * v;
        }
        for (int off = 32; off; off >>= 1) {
            sum += __shfl_xor(sum, off, 64);
            sq  += __shfl_xor(sq,  off, 64);
        }
        float mu  = sum * (1.f / DMODEL);
        float var = sq * (1.f / DMODEL) - mu * mu;
        float inv = rsqrtf(var + LN_EPS);
        int row = base_row + r;
        if (row < BQ + FEW) {
            float* outp = (row < BQ) ? (query_g + row * DMODEL) : (sup_ln + (row - BQ) * DMODEL);
            for (int i = 0; i < 4; ++i) {
                int dd = l + 64 * i;
                outp[dd] = (os[r][dd] - mu) * inv * lng[dd] + lnb[dd];
            }
        }
    }
}

// ---------------------------------------------------------------------------
// Kernel 3: s = mean over the 5 support rows (after LN)
// ---------------------------------------------------------------------------
__global__ __launch_bounds__(256) void mean_s_kernel(
    const float* __restrict__ sup_ln, float* __restrict__ s_vec)
{
    int t = threadIdx.x;
    float acc = 0.f;
    for (int i = 0; i < FEW; ++i) acc += sup_ln[i * DMODEL + t];
    s_vec[t] = acc * (1.f / FEW);
}

// ---------------------------------------------------------------------------
// Kernel 4: sWp[p] = sum_e s[e] * W_hh[row(p), 256+e], p = pp*256+q, row = pp*512+q.
// Only the live gate lanes (q<256 of each gate) are computed.
// Grid 16 x 256: one wave per output group, 16 outputs per wave, coalesced.
// ---------------------------------------------------------------------------
__global__ __launch_bounds__(256) void sWp_kernel(
    const float* __restrict__ s_vec, const float* __restrict__ W_hh,
    float* __restrict__ sWp)
{
    int w = threadIdx.x >> 6, l = threadIdx.x & 63;
    int wave_id = blockIdx.x * 4 + w;   // 0..63
    for (int i = 0; i < 16; ++i) {
        int p = wave_id * 16 + i;       // 0..1023
        int pp = p >> 8, q = p & 255;
        const float* wr = W_hh + (pp * 512 + q) * HIDN + 256;
        float part = 0.f;
        for (int e = l; e < 256; e += 64) part += s_vec[e] * wr[e];
        for (int off = 32; off; off >>= 1) part += __shfl_xor(part, off, 64);
        if (l == 0) sWp[p] = part;
    }
}

// ---------------------------------------------------------------------------
// Kernel 5: LSTM base + step 0.
// base0p[n, pp*256+q] = query_g[n] . W_ih[pp*512+q, :] + b_ih + b_hh  (live lanes only)
// Step 0 (h_r = 0): c = sig(i)*tanh(g); h = query_g + sig(o)*tanh(c).
// 8 samples per block, thread t owns gate lane q=t for all 4 gates.
// ---------------------------------------------------------------------------
#define LS_SAMP 8
__global__ __launch_bounds__(256) void lstm_base_kernel(
    const float* __restrict__ query_g, const float* __restrict__ W_ih,
    const float* __restrict__ b_ih, const float* __restrict__ b_hh,
    float* __restrict__ base0p, float* __restrict__ c_st, float* __restrict__ h_st)
{
    __shared__ __align__(16) float xs[LS_SAMP][DMODEL];
    int t = threadIdx.x;
    int n0 = blockIdx.x * LS_SAMP;
    for (int r = 0; r < LS_SAMP; ++r) xs[r][t] = query_g[(n0 + r) * DMODEL + t];
    __syncthreads();

    float acc[4][LS_SAMP];
    #pragma unroll
    for (int pp = 0; pp < 4; ++pp)
        #pragma unroll
        for (int r = 0; r < LS_SAMP; ++r) acc[pp][r] = 0.f;

    for (int pp = 0; pp < 4; ++pp) {
        const float4* wrow = (const float4*)(W_ih + (pp * 512 + t) * DMODEL);
        for (int e = 0; e < DMODEL / 4; ++e) {
            float4 wv = wrow[e];
            #pragma unroll
            for (int r = 0; r < LS_SAMP; ++r) {
                float4 xv = ((const float4*)xs[r])[e];
                acc[pp][r] += wv.x * xv.x + wv.y * xv.y + wv.z * xv.z + wv.w * xv.w;
            }
        }
    }
    float bi[4];
    #pragma unroll
    for (int pp = 0; pp < 4; ++pp) bi[pp] = b_ih[pp * 512 + t] + b_hh[pp * 512 + t];

    for (int r = 0; r < LS_SAMP; ++r) {
        int n = n0 + r;
        float gi = acc[0][r] + bi[0];
        float gf = acc[1][r] + bi[1];
        float gg = acc[2][r] + bi[2];
        float go = acc[3][r] + bi[3];
        base0p[n * 1024 + 0 * 256 + t] = gi;
        base0p[n * 1024 + 1 * 256 + t] = gf;
        base0p[n * 1024 + 2 * 256 + t] = gg;
        base0p[n * 1024 + 3 * 256 + t] = go;
        float cc = sigmoidf_(gi) * tanhf(gg);      // c0 = 0 -> f-term drops
        c_st[n * DMODEL + t] = cc;
        h_st[n * DMODEL + t] = xs[r][t] + sigmoidf_(go) * tanhf(cc);
    }
}

// ---------------------------------------------------------------------------
// Kernel 6: LSTM step (t=1..3): gates = base0p + sWp + h @ W_hh[:, :256].T (live lanes)
// then c,h update. In-place on c_st/h_st; each block owns its 8 samples.
// ---------------------------------------------------------------------------
__global__ __launch_bounds__(256) void lstm_step_kernel(
    const float* __restrict__ query_g, const float* __restrict__ W_hh,
    const float* __restrict__ base0p, const float* __restrict__ sWp,
    float* __restrict__ c_st, float* __restrict__ h_st)
{
    __shared__ __align__(16) float xs[LS_SAMP][DMODEL];   // h rows
    int t = threadIdx.x;
    int n0 = blockIdx.x * LS_SAMP;
    for (int r = 0; r < LS_SAMP; ++r) xs[r][t] = h_st[(n0 + r) * DMODEL + t];
    __syncthreads();

    float acc[4][LS_SAMP];
    #pragma unroll
    for (int pp = 0; pp < 4; ++pp)
        #pragma unroll
        for (int r = 0; r < LS_SAMP; ++r) acc[pp][r] = 0.f;

    for (int pp = 0; pp < 4; ++pp) {
        const float4* wrow = (const float4*)(W_hh + (pp * 512 + t) * HIDN);  // cols 0..255
        for (int e = 0; e < DMODEL / 4; ++e) {
            float4 wv = wrow[e];
            #pragma unroll
            for (int r = 0; r < LS_SAMP; ++r) {
                float4 xv = ((const float4*)xs[r])[e];
                acc[pp][r] += wv.x * xv.x + wv.y * xv.y + wv.z * xv.z + wv.w * xv.w;
            }
        }
    }
    float sw[4];
    #pragma unroll
    for (int pp = 0; pp < 4; ++pp) sw[pp] = sWp[pp * 256 + t];

    for (int r = 0; r < LS_SAMP; ++r) {
        int n = n0 + r;
        float gi = acc[0][r] + base0p[n * 1024 + 0 * 256 + t] + sw[0];
        float gf = acc[1][r] + base0p[n * 1024 + 1 * 256 + t] + sw[1];
        float gg = acc[2][r] + base0p[n * 1024 + 2 * 256 + t] + sw[2];
        float go = acc[3][r] + base0p[n * 1024 + 3 * 256 + t] + sw[3];
        float cold = c_st[n * DMODEL + t];
        float cc = sigmoidf_(gf) * cold + sigmoidf_(gi) * tanhf(gg);
        c_st[n * DMODEL + t] = cc;
        h_st[n * DMODEL + t] = query_g[n * DMODEL + t] + sigmoidf_(go) * tanhf(cc);
    }
}

// ---------------------------------------------------------------------------
// Kernel 7: out[n] = dot(h[n], s). Grid 16 x 256: 64 waves x 16 samples.
// ---------------------------------------------------------------------------
__global__ __launch_bounds__(256) void final_kernel(
    const float* __restrict__ h_st, const float* __restrict__ s_vec,
    float* __restrict__ out)
{
    int w = threadIdx.x >> 6, l = threadIdx.x & 63;
    int wave_id = blockIdx.x * 4 + w;
    for (int i = 0; i < 16; ++i) {
        int n = wave_id * 16 + i;
        float part = 0.f;
        for (int e = l; e < DMODEL; e += 64) part += h_st[n * DMODEL + e] * s_vec[e];
        for (int off = 32; off; off >>= 1) part += __shfl_xor(part, off, 64);
        if (l == 0) out[n] = part;
    }
}

// ---------------------------------------------------------------------------
extern "C" void kernel_launch(void* const* d_in, const int* in_sizes, int n_in,
                              void* d_out, int out_size, void* d_ws, size_t ws_size,
                              hipStream_t stream)
{
    const int*   qlc  = (const int*)d_in[0];
    const int*   qrc  = (const int*)d_in[1];
    const int*   slc  = (const int*)d_in[2];
    const int*   src_ = (const int*)d_in[3];
    // d_in[4..7]: degrees — unused by the reference
    const float* emb   = (const float*)d_in[8];
    const float* gcnW  = (const float*)d_in[9];
    const float* gcnwb = (const float*)d_in[10];
    const float* gcnb  = (const float*)d_in[11];
    const float* p1W   = (const float*)d_in[12];
    const float* p1b   = (const float*)d_in[13];
    const float* p2W   = (const float*)d_in[14];
    const float* p2b   = (const float*)d_in[15];
    const float* lng   = (const float*)d_in[16];
    const float* lnb   = (const float*)d_in[17];
    const float* W_ih  = (const float*)d_in[18];
    const float* W_hh  = (const float*)d_in[19];
    const float* b_ih  = (const float*)d_in[20];
    const float* b_hh  = (const float*)d_in[21];
    float* out = (float*)d_out;

    // Workspace layout (~8.4 MB total)
    char* ws = (char*)d_ws;
    float* qn      = (float*)(ws + 0);         // 1024*256*4 = 1048576
    float* sn      = (float*)(ws + 1048576);   // 5*256*4    = 5120
    float* query_g = (float*)(ws + 1053696);   // 1048576
    float* sup_ln  = (float*)(ws + 2102272);   // 5120
    float* s_vec   = (float*)(ws + 2107392);   // 1024
    float* sWp     = (float*)(ws + 2108416);   // 4096
    float* base0p  = (float*)(ws + 2112512);   // 1024*1024*4 = 4194304
    float* c_st    = (float*)(ws + 6306816);   // 1048576
    float* h_st    = (float*)(ws + 7355392);   // 1048576
    (void)ws_size; (void)in_sizes; (void)n_in; (void)out_size;

    neighbor_kernel<<<2 * BQ + 2 * FEW, 256, 0, stream>>>(
        qlc, qrc, slc, src_, emb, gcnW, gcnwb, gcnb, qn, sn);
    support_enc_kernel<<<(BQ + FEW + SE_ROWS - 1) / SE_ROWS, 256, 0, stream>>>(
        qn, sn, p1W, p1b, p2W, p2b, lng, lnb, query_g, sup_ln);
    mean_s_kernel<<<1, 256, 0, stream>>>(sup_ln, s_vec);
    sWp_kernel<<<16, 256, 0, stream>>>(s_vec, W_hh, sWp);
    lstm_base_kernel<<<BQ / LS_SAMP, 256, 0, stream>>>(
        query_g, W_ih, b_ih, b_hh, base0p, c_st, h_st);
    for (int st = 0; st < 3; ++st)
        lstm_step_kernel<<<BQ / LS_SAMP, 256, 0, stream>>>(
            query_g, W_hh, base0p, sWp, c_st, h_st);
    final_kernel<<<16, 256, 0, stream>>>(h_st, s_vec, out);
}

// Round 2
// 653.549 us; speedup vs baseline: 1.7400x; 1.7400x over previous
//
#include <hip/hip_runtime.h>
#include <math.h>

// Problem constants
#define EMBED   128
#define DMODEL  256   // 2*EMBED
#define DINNER  512
#define HIDN    512
#define NBK     200
#define BQ      1024
#define FEW     5
#define PAD_IDX 200000
#define LN_EPS  1e-5f

typedef short          s16x8  __attribute__((ext_vector_type(8)));
typedef float          f32x16 __attribute__((ext_vector_type(16)));
typedef unsigned int   u32;
typedef u32            u32x4  __attribute__((ext_vector_type(4)));

__device__ __forceinline__ float sigmoidf_(float x) { return 1.0f / (1.0f + expf(-x)); }

// float -> bf16 (round-to-nearest-even), as raw u16 in low bits
__device__ __forceinline__ u32 f2bf(float f) {
    u32 u = __builtin_bit_cast(u32, f);
    u += 0x7fffu + ((u >> 16) & 1u);
    return u >> 16;
}
// pack 8 floats (two float4) into a bf16x8 fragment
__device__ __forceinline__ s16x8 pack8(float4 a, float4 b) {
    u32x4 q;
    q.x = f2bf(a.x) | (f2bf(a.y) << 16);
    q.y = f2bf(a.z) | (f2bf(a.w) << 16);
    q.z = f2bf(b.x) | (f2bf(b.y) << 16);
    q.w = f2bf(b.z) | (f2bf(b.w) << 16);
    return __builtin_bit_cast(s16x8, q);
}

// ---------------------------------------------------------------------------
// Kernel 1: neighbor encoder, MFMA bf16 32x32x16.
// Block = one (sample, side); 4 waves, wave w owns d-columns [w*32, w*32+32).
// A = W (M=d, K=e) held in registers: 16 kstep frags. B = X^T (N=k-row, K=e)
// gathered from emb per 32-row n-tile, converted to bf16 in-register.
// Epilogue: masked max over k-rows (cols) of raw dots, then leaky+bias+tanh
// (monotone ops commute past the max).
// ---------------------------------------------------------------------------
__global__ __launch_bounds__(256) void neighbor_kernel(
    const int* __restrict__ qlc, const int* __restrict__ qrc,
    const int* __restrict__ slc, const int* __restrict__ src_,
    const float* __restrict__ emb, const float* __restrict__ W,
    const float* __restrict__ wb,  const float* __restrict__ bb,
    float* __restrict__ qn, float* __restrict__ sn)
{
    int b = blockIdx.x;
    const int* conn; float* out; int n; int side;
    if (b < BQ)                { conn = qlc;  n = b;            side = 0; out = qn; }
    else if (b < 2*BQ)         { conn = qrc;  n = b - BQ;       side = 1; out = qn; }
    else if (b < 2*BQ + FEW)   { conn = slc;  n = b - 2*BQ;     side = 0; out = sn; }
    else                       { conn = src_; n = b - 2*BQ-FEW; side = 1; out = sn; }

    int t = threadIdx.x;
    int w = t >> 6, l = t & 63;
    int d0 = w * 32;
    int m31 = l & 31, half = l >> 5;

    // A-frags: afrag[ks] holds W[d0+m31][ks*16 + half*8 .. +7]
    s16x8 afrag[16];
    const float* wrow = W + (d0 + m31) * DMODEL + half * 8;
    #pragma unroll
    for (int ks = 0; ks < 16; ++ks) {
        float4 x0 = *(const float4*)(wrow + ks * 16);
        float4 x1 = *(const float4*)(wrow + ks * 16 + 4);
        afrag[ks] = pack8(x0, x1);
    }

    // Preload this lane's connection indices for all 7 n-tiles
    const int* crow = conn + n * NBK * 2;
    int relv[7], entv[7];
    #pragma unroll
    for (int nt = 0; nt < 7; ++nt) {
        int row = nt * 32 + m31;
        int rel = PAD_IDX, ent = PAD_IDX;
        if (row < NBK) { rel = crow[2 * row]; ent = crow[2 * row + 1]; }
        relv[nt] = rel; entv[nt] = ent;
    }

    float vm[16];
    #pragma unroll
    for (int r = 0; r < 16; ++r) vm[r] = -INFINITY;

    #pragma unroll
    for (int nt = 0; nt < 7; ++nt) {
        int rel = relv[nt], ent = entv[nt];
        bool valid = (rel != PAD_IDX) && (ent != PAD_IDX);
        if (!__any((int)valid)) continue;          // wave-uniform tile skip
        int ri = valid ? rel : PAD_IDX;            // PAD row of emb is zeros
        int ei = valid ? ent : PAD_IDX;
        const float* prel = emb + (size_t)ri * EMBED + half * 8;
        const float* pent = emb + (size_t)ei * EMBED + half * 8;

        f32x16 acc0 = {0.f,0.f,0.f,0.f,0.f,0.f,0.f,0.f,0.f,0.f,0.f,0.f,0.f,0.f,0.f,0.f};
        f32x16 acc1 = acc0;
        #pragma unroll
        for (int ks = 0; ks < 8; ++ks) {           // e in [0,128): emb[rel]
            float4 x0 = *(const float4*)(prel + ks * 16);
            float4 x1 = *(const float4*)(prel + ks * 16 + 4);
            acc0 = __builtin_amdgcn_mfma_f32_32x32x16_bf16(afrag[ks], pack8(x0, x1), acc0, 0, 0, 0);
        }
        #pragma unroll
        for (int ks = 0; ks < 8; ++ks) {           // e in [128,256): emb[ent]
            float4 x0 = *(const float4*)(pent + ks * 16);
            float4 x1 = *(const float4*)(pent + ks * 16 + 4);
            acc1 = __builtin_amdgcn_mfma_f32_32x32x16_bf16(afrag[8 + ks], pack8(x0, x1), acc1, 0, 0, 0);
        }
        #pragma unroll
        for (int r = 0; r < 16; ++r) {
            float v = valid ? (acc0[r] + acc1[r]) : -INFINITY;
            vm[r] = fmaxf(vm[r], v);
        }
    }

    // Max across the 32 cols (k-rows) held in each 32-lane half
    #pragma unroll
    for (int off = 1; off < 32; off <<= 1) {
        #pragma unroll
        for (int r = 0; r < 16; ++r)
            vm[r] = fmaxf(vm[r], __shfl_xor(vm[r], off, 64));
    }

    if (m31 == 0) {
        #pragma unroll
        for (int r = 0; r < 16; ++r) {
            int d = d0 + (r & 3) + 8 * (r >> 2) + 4 * half;
            float p = vm[r] + wb[d] + bb[d];
            p = (p >= 0.f) ? p : 0.1f * p;         // leaky_relu(0.1)
            out[n * DMODEL + side * EMBED + d] = tanhf(p);
        }
    }
}

// ---------------------------------------------------------------------------
// Kernel 2: support encoder (MLP + residual + LN) for 1029 rows. 4 rows/block.
// ---------------------------------------------------------------------------
#define SE_ROWS 4
__global__ __launch_bounds__(256) void support_enc_kernel(
    const float* __restrict__ qn, const float* __restrict__ sn,
    const float* __restrict__ p1W, const float* __restrict__ p1b,
    const float* __restrict__ p2W, const float* __restrict__ p2b,
    const float* __restrict__ lng, const float* __restrict__ lnb,
    float* __restrict__ query_g, float* __restrict__ sup_ln)
{
    __shared__ __align__(16) float xs[SE_ROWS][DMODEL];
    __shared__ __align__(16) float hs[SE_ROWS][DINNER];
    __shared__ __align__(16) float os[SE_ROWS][DMODEL];
    int t = threadIdx.x;
    int base_row = blockIdx.x * SE_ROWS;

    for (int r = 0; r < SE_ROWS; ++r) {
        int row = base_row + r;
        float v = 0.f;
        if (row < BQ + FEW)
            v = (row < BQ) ? qn[row * DMODEL + t] : sn[(row - BQ) * DMODEL + t];
        xs[r][t] = v;
    }
    __syncthreads();

    // h = relu(x @ p1W.T + p1b): thread t does j = t and t+256
    for (int jj = 0; jj < 2; ++jj) {
        int j = t + jj * 256;
        const float4* wrow = (const float4*)(p1W + j * DMODEL);
        float acc[SE_ROWS];
        #pragma unroll
        for (int r = 0; r < SE_ROWS; ++r) acc[r] = 0.f;
        for (int e = 0; e < DMODEL / 4; ++e) {
            float4 wv = wrow[e];
            #pragma unroll
            for (int r = 0; r < SE_ROWS; ++r) {
                float4 xv = ((const float4*)xs[r])[e];
                acc[r] += wv.x * xv.x + wv.y * xv.y + wv.z * xv.z + wv.w * xv.w;
            }
        }
        float bj = p1b[j];
        #pragma unroll
        for (int r = 0; r < SE_ROWS; ++r) hs[r][j] = fmaxf(acc[r] + bj, 0.f);
    }
    __syncthreads();

    // o = h @ p2W.T + p2b + x
    {
        const float4* wrow = (const float4*)(p2W + t * DINNER);
        float acc[SE_ROWS];
        #pragma unroll
        for (int r = 0; r < SE_ROWS; ++r) acc[r] = 0.f;
        for (int e = 0; e < DINNER / 4; ++e) {
            float4 wv = wrow[e];
            #pragma unroll
            for (int r = 0; r < SE_ROWS; ++r) {
                float4 hv = ((const float4*)hs[r])[e];
                acc[r] += wv.x * hv.x + wv.y * hv.y + wv.z * hv.z + wv.w * hv.w;
            }
        }
        float bt = p2b[t];
        #pragma unroll
        for (int r = 0; r < SE_ROWS; ++r) os[r][t] = acc[r] + bt + xs[r][t];
    }
    __syncthreads();

    // LayerNorm: wave w handles row w
    int w = t >> 6, l = t & 63;
    {
        int r = w;
        float sum = 0.f, sq = 0.f;
        for (int i = 0; i < 4; ++i) {
            float v = os[r][l + 64 * i];
            sum += v; sq += v * v;
        }
        for (int off = 32; off; off >>= 1) {
            sum += __shfl_xor(sum, off, 64);
            sq  += __shfl_xor(sq,  off, 64);
        }
        float mu  = sum * (1.f / DMODEL);
        float var = sq * (1.f / DMODEL) - mu * mu;
        float inv = rsqrtf(var + LN_EPS);
        int row = base_row + r;
        if (row < BQ + FEW) {
            float* outp = (row < BQ) ? (query_g + row * DMODEL) : (sup_ln + (row - BQ) * DMODEL);
            for (int i = 0; i < 4; ++i) {
                int dd = l + 64 * i;
                outp[dd] = (os[r][dd] - mu) * inv * lng[dd] + lnb[dd];
            }
        }
    }
}

// ---------------------------------------------------------------------------
// Kernel 3: s = mean over the 5 support rows (after LN)
// ---------------------------------------------------------------------------
__global__ __launch_bounds__(256) void mean_s_kernel(
    const float* __restrict__ sup_ln, float* __restrict__ s_vec)
{
    int t = threadIdx.x;
    float acc = 0.f;
    for (int i = 0; i < FEW; ++i) acc += sup_ln[i * DMODEL + t];
    s_vec[t] = acc * (1.f / FEW);
}

// ---------------------------------------------------------------------------
// Kernel 4: sWp[p] = sum_e s[e] * W_hh[row(p), 256+e]; live gate lanes only.
// ---------------------------------------------------------------------------
__global__ __launch_bounds__(256) void sWp_kernel(
    const float* __restrict__ s_vec, const float* __restrict__ W_hh,
    float* __restrict__ sWp)
{
    int w = threadIdx.x >> 6, l = threadIdx.x & 63;
    int wave_id = blockIdx.x * 4 + w;   // 0..63
    for (int i = 0; i < 16; ++i) {
        int p = wave_id * 16 + i;       // 0..1023
        int pp = p >> 8, q = p & 255;
        const float* wr = W_hh + (pp * 512 + q) * HIDN + 256;
        float part = 0.f;
        for (int e = l; e < 256; e += 64) part += s_vec[e] * wr[e];
        for (int off = 32; off; off >>= 1) part += __shfl_xor(part, off, 64);
        if (l == 0) sWp[p] = part;
    }
}

// ---------------------------------------------------------------------------
// Kernel 5: LSTM base + step 0 (live gate lanes only). 4 samples/block.
// ---------------------------------------------------------------------------
#define LS_SAMP 4
__global__ __launch_bounds__(256) void lstm_base_kernel(
    const float* __restrict__ query_g, const float* __restrict__ W_ih,
    const float* __restrict__ b_ih, const float* __restrict__ b_hh,
    float* __restrict__ base0p, float* __restrict__ c_st, float* __restrict__ h_st)
{
    __shared__ __align__(16) float xs[LS_SAMP][DMODEL];
    int t = threadIdx.x;
    int n0 = blockIdx.x * LS_SAMP;
    for (int r = 0; r < LS_SAMP; ++r) xs[r][t] = query_g[(n0 + r) * DMODEL + t];
    __syncthreads();

    float acc[4][LS_SAMP];
    #pragma unroll
    for (int pp = 0; pp < 4; ++pp)
        #pragma unroll
        for (int r = 0; r < LS_SAMP; ++r) acc[pp][r] = 0.f;

    for (int pp = 0; pp < 4; ++pp) {
        const float4* wrow = (const float4*)(W_ih + (pp * 512 + t) * DMODEL);
        for (int e = 0; e < DMODEL / 4; ++e) {
            float4 wv = wrow[e];
            #pragma unroll
            for (int r = 0; r < LS_SAMP; ++r) {
                float4 xv = ((const float4*)xs[r])[e];
                acc[pp][r] += wv.x * xv.x + wv.y * xv.y + wv.z * xv.z + wv.w * xv.w;
            }
        }
    }
    float bi[4];
    #pragma unroll
    for (int pp = 0; pp < 4; ++pp) bi[pp] = b_ih[pp * 512 + t] + b_hh[pp * 512 + t];

    for (int r = 0; r < LS_SAMP; ++r) {
        int n = n0 + r;
        float gi = acc[0][r] + bi[0];
        float gf = acc[1][r] + bi[1];
        float gg = acc[2][r] + bi[2];
        float go = acc[3][r] + bi[3];
        base0p[n * 1024 + 0 * 256 + t] = gi;
        base0p[n * 1024 + 1 * 256 + t] = gf;
        base0p[n * 1024 + 2 * 256 + t] = gg;
        base0p[n * 1024 + 3 * 256 + t] = go;
        float cc = sigmoidf_(gi) * tanhf(gg);      // c0 = 0 -> f-term drops
        c_st[n * DMODEL + t] = cc;
        h_st[n * DMODEL + t] = xs[r][t] + sigmoidf_(go) * tanhf(cc);
    }
}

// ---------------------------------------------------------------------------
// Kernel 6: LSTM step: gates = base0p + sWp + h @ W_hh[:, :256].T (live lanes)
// ---------------------------------------------------------------------------
__global__ __launch_bounds__(256) void lstm_step_kernel(
    const float* __restrict__ query_g, const float* __restrict__ W_hh,
    const float* __restrict__ base0p, const float* __restrict__ sWp,
    float* __restrict__ c_st, float* __restrict__ h_st)
{
    __shared__ __align__(16) float xs[LS_SAMP][DMODEL];   // h rows
    int t = threadIdx.x;
    int n0 = blockIdx.x * LS_SAMP;
    for (int r = 0; r < LS_SAMP; ++r) xs[r][t] = h_st[(n0 + r) * DMODEL + t];
    __syncthreads();

    float acc[4][LS_SAMP];
    #pragma unroll
    for (int pp = 0; pp < 4; ++pp)
        #pragma unroll
        for (int r = 0; r < LS_SAMP; ++r) acc[pp][r] = 0.f;

    for (int pp = 0; pp < 4; ++pp) {
        const float4* wrow = (const float4*)(W_hh + (pp * 512 + t) * HIDN);  // cols 0..255
        for (int e = 0; e < DMODEL / 4; ++e) {
            float4 wv = wrow[e];
            #pragma unroll
            for (int r = 0; r < LS_SAMP; ++r) {
                float4 xv = ((const float4*)xs[r])[e];
                acc[pp][r] += wv.x * xv.x + wv.y * xv.y + wv.z * xv.z + wv.w * xv.w;
            }
        }
    }
    float sw[4];
    #pragma unroll
    for (int pp = 0; pp < 4; ++pp) sw[pp] = sWp[pp * 256 + t];

    for (int r = 0; r < LS_SAMP; ++r) {
        int n = n0 + r;
        float gi = acc[0][r] + base0p[n * 1024 + 0 * 256 + t] + sw[0];
        float gf = acc[1][r] + base0p[n * 1024 + 1 * 256 + t] + sw[1];
        float gg = acc[2][r] + base0p[n * 1024 + 2 * 256 + t] + sw[2];
        float go = acc[3][r] + base0p[n * 1024 + 3 * 256 + t] + sw[3];
        float cold = c_st[n * DMODEL + t];
        float cc = sigmoidf_(gf) * cold + sigmoidf_(gi) * tanhf(gg);
        c_st[n * DMODEL + t] = cc;
        h_st[n * DMODEL + t] = query_g[n * DMODEL + t] + sigmoidf_(go) * tanhf(cc);
    }
}

// ---------------------------------------------------------------------------
// Kernel 7: out[n] = dot(h[n], s)
// ---------------------------------------------------------------------------
__global__ __launch_bounds__(256) void final_kernel(
    const float* __restrict__ h_st, const float* __restrict__ s_vec,
    float* __restrict__ out)
{
    int w = threadIdx.x >> 6, l = threadIdx.x & 63;
    int wave_id = blockIdx.x * 4 + w;
    for (int i = 0; i < 16; ++i) {
        int n = wave_id * 16 + i;
        float part = 0.f;
        for (int e = l; e < DMODEL; e += 64) part += h_st[n * DMODEL + e] * s_vec[e];
        for (int off = 32; off; off >>= 1) part += __shfl_xor(part, off, 64);
        if (l == 0) out[n] = part;
    }
}

// ---------------------------------------------------------------------------
extern "C" void kernel_launch(void* const* d_in, const int* in_sizes, int n_in,
                              void* d_out, int out_size, void* d_ws, size_t ws_size,
                              hipStream_t stream)
{
    const int*   qlc  = (const int*)d_in[0];
    const int*   qrc  = (const int*)d_in[1];
    const int*   slc  = (const int*)d_in[2];
    const int*   src_ = (const int*)d_in[3];
    // d_in[4..7]: degrees — unused by the reference
    const float* emb   = (const float*)d_in[8];
    const float* gcnW  = (const float*)d_in[9];
    const float* gcnwb = (const float*)d_in[10];
    const float* gcnb  = (const float*)d_in[11];
    const float* p1W   = (const float*)d_in[12];
    const float* p1b   = (const float*)d_in[13];
    const float* p2W   = (const float*)d_in[14];
    const float* p2b   = (const float*)d_in[15];
    const float* lng   = (const float*)d_in[16];
    const float* lnb   = (const float*)d_in[17];
    const float* W_ih  = (const float*)d_in[18];
    const float* W_hh  = (const float*)d_in[19];
    const float* b_ih  = (const float*)d_in[20];
    const float* b_hh  = (const float*)d_in[21];
    float* out = (float*)d_out;

    // Workspace layout (~8.4 MB total)
    char* ws = (char*)d_ws;
    float* qn      = (float*)(ws + 0);         // 1048576
    float* sn      = (float*)(ws + 1048576);   // 5120
    float* query_g = (float*)(ws + 1053696);   // 1048576
    float* sup_ln  = (float*)(ws + 2102272);   // 5120
    float* s_vec   = (float*)(ws + 2107392);   // 1024
    float* sWp     = (float*)(ws + 2108416);   // 4096
    float* base0p  = (float*)(ws + 2112512);   // 4194304
    float* c_st    = (float*)(ws + 6306816);   // 1048576
    float* h_st    = (float*)(ws + 7355392);   // 1048576
    (void)ws_size; (void)in_sizes; (void)n_in; (void)out_size;

    neighbor_kernel<<<2 * BQ + 2 * FEW, 256, 0, stream>>>(
        qlc, qrc, slc, src_, emb, gcnW, gcnwb, gcnb, qn, sn);
    support_enc_kernel<<<(BQ + FEW + SE_ROWS - 1) / SE_ROWS, 256, 0, stream>>>(
        qn, sn, p1W, p1b, p2W, p2b, lng, lnb, query_g, sup_ln);
    mean_s_kernel<<<1, 256, 0, stream>>>(sup_ln, s_vec);
    sWp_kernel<<<16, 256, 0, stream>>>(s_vec, W_hh, sWp);
    lstm_base_kernel<<<BQ / LS_SAMP, 256, 0, stream>>>(
        query_g, W_ih, b_ih, b_hh, base0p, c_st, h_st);
    for (int st = 0; st < 3; ++st)
        lstm_step_kernel<<<BQ / LS_SAMP, 256, 0, stream>>>(
            query_g, W_hh, base0p, sWp, c_st, h_st);
    final_kernel<<<16, 256, 0, stream>>>(h_st, s_vec, out);
}

// Round 3
// 527.457 us; speedup vs baseline: 2.1560x; 1.2391x over previous
//
#include <hip/hip_runtime.h>
#include <math.h>

// Problem constants
#define EMBED   128
#define DMODEL  256   // 2*EMBED
#define DINNER  512
#define HIDN    512
#define NBK     200
#define BQ      1024
#define FEW     5
#define PAD_IDX 200000
#define LN_EPS  1e-5f
#define NTILES  7

typedef short          s16x4  __attribute__((ext_vector_type(4)));
typedef short          s16x8  __attribute__((ext_vector_type(8)));
typedef float          f32x16 __attribute__((ext_vector_type(16)));
typedef unsigned int   u32;

__device__ __forceinline__ float sigmoidf_(float x) { return 1.0f / (1.0f + expf(-x)); }

// float -> bf16 (round-to-nearest-even), raw u16
__device__ __forceinline__ u32 f2bf(float f) {
    u32 u = __builtin_bit_cast(u32, f);
    u += 0x7fffu + ((u >> 16) & 1u);
    return u >> 16;
}
__device__ __forceinline__ s16x8 pack8(float4 a, float4 b) {
    typedef u32 u32x4_ __attribute__((ext_vector_type(4)));
    u32x4_ q;
    q.x = f2bf(a.x) | (f2bf(a.y) << 16);
    q.y = f2bf(a.z) | (f2bf(a.w) << 16);
    q.z = f2bf(b.x) | (f2bf(b.y) << 16);
    q.w = f2bf(b.z) | (f2bf(b.w) << 16);
    return __builtin_bit_cast(s16x8, q);
}

// ---------------------------------------------------------------------------
// Kernel 1: neighbor encoder, MFMA bf16 32x32x16 with cooperative LDS staging.
// Block = one (sample, side); 4 waves, wave w owns d-columns [w*32, w*32+32).
// Per 32-k-row tile: 256 threads gather 64 emb rows (32 rel + 32 ent), convert
// to bf16 into LDS once; every wave then reads its B-fragments from LDS.
// LDS row stride = 66 u32 (132 bf16): bank step 2 -> free 2-way aliasing.
// Epilogue: masked max over k of raw dots, then bias+leaky+tanh (monotone).
// ---------------------------------------------------------------------------
__global__ __launch_bounds__(256) void neighbor_kernel(
    const int* __restrict__ qlc, const int* __restrict__ qrc,
    const int* __restrict__ slc, const int* __restrict__ src_,
    const float* __restrict__ emb, const float* __restrict__ W,
    const float* __restrict__ wb,  const float* __restrict__ bb,
    float* __restrict__ qn, float* __restrict__ sn)
{
    int b = blockIdx.x;
    const int* conn; float* out; int n; int side;
    if (b < BQ)                { conn = qlc;  n = b;            side = 0; out = qn; }
    else if (b < 2*BQ)         { conn = qrc;  n = b - BQ;       side = 1; out = qn; }
    else if (b < 2*BQ + FEW)   { conn = slc;  n = b - 2*BQ;     side = 0; out = sn; }
    else                       { conn = src_; n = b - 2*BQ-FEW; side = 1; out = sn; }

    int t = threadIdx.x;
    int w = t >> 6, l = t & 63;
    int d0 = w * 32;
    int m31 = l & 31, half = l >> 5;

    __shared__ __align__(16) u32 bs[64 * 66];   // 16.9 KB staging

    // A-frags: afrag[ks] = W[d0+m31][ks*16 + half*8 .. +7] in bf16
    s16x8 afrag[16];
    const float* wrow = W + (d0 + m31) * DMODEL + half * 8;
    #pragma unroll
    for (int ks = 0; ks < 16; ++ks) {
        float4 x0 = *(const float4*)(wrow + ks * 16);
        float4 x1 = *(const float4*)(wrow + ks * 16 + 4);
        afrag[ks] = pack8(x0, x1);
    }

    // Column-validity bitmask for this lane's column m31 (same for all waves)
    const int* crow = conn + n * NBK * 2;
    u32 vmask = 0;
    #pragma unroll
    for (int nt = 0; nt < NTILES; ++nt) {
        int krow = nt * 32 + m31;
        if (krow < NBK) {
            int rel = crow[2 * krow], ent = crow[2 * krow + 1];
            if (rel != PAD_IDX && ent != PAD_IDX) vmask |= (1u << nt);
        }
    }

    // Gather mapping: thread t -> row gr (0..63), quarter gq (32 floats)
    int gr = t >> 2;
    int gq = t & 3;
    int g_is_ent = (gr >= 32);
    int g_m = gr & 31;

    float vm[16];
    #pragma unroll
    for (int r = 0; r < 16; ++r) vm[r] = -INFINITY;

    for (int nt = 0; nt < NTILES; ++nt) {
        // uniform across all waves: vmask depends only on m31
        if (!__any((int)((vmask >> nt) & 1u))) continue;

        // ---- cooperative gather of this tile's 64 rows ----
        int krow = nt * 32 + g_m;
        int rel = PAD_IDX, ent = PAD_IDX;
        if (krow < NBK) { rel = crow[2 * krow]; ent = crow[2 * krow + 1]; }
        int gvalid = (rel != PAD_IDX) && (ent != PAD_IDX);
        int srcrow = gvalid ? (g_is_ent ? ent : rel) : PAD_IDX;  // PAD row = zeros
        const float4* gp = (const float4*)(emb + (size_t)srcrow * EMBED + gq * 32);
        float4 f[8];
        #pragma unroll
        for (int i = 0; i < 8; ++i) f[i] = gp[i];

        __syncthreads();   // prior tile's LDS reads complete
        u32* dst = bs + gr * 66 + gq * 16;
        #pragma unroll
        for (int i = 0; i < 8; ++i) {
            dst[2 * i]     = f2bf(f[i].x) | (f2bf(f[i].y) << 16);
            dst[2 * i + 1] = f2bf(f[i].z) | (f2bf(f[i].w) << 16);
        }
        __syncthreads();   // staged tile visible

        // ---- MFMA from LDS ----
        const u32* rrel = bs + m31 * 66 + half * 4;
        const u32* rent = bs + (32 + m31) * 66 + half * 4;
        f32x16 acc0 = {0.f,0.f,0.f,0.f,0.f,0.f,0.f,0.f,0.f,0.f,0.f,0.f,0.f,0.f,0.f,0.f};
        f32x16 acc1 = acc0;
        #pragma unroll
        for (int ks = 0; ks < 8; ++ks) {
            s16x4 lo = *(const s16x4*)(rrel + ks * 8);
            s16x4 hi = *(const s16x4*)(rrel + ks * 8 + 2);
            s16x8 bf = __builtin_shufflevector(lo, hi, 0, 1, 2, 3, 4, 5, 6, 7);
            acc0 = __builtin_amdgcn_mfma_f32_32x32x16_bf16(afrag[ks], bf, acc0, 0, 0, 0);
        }
        #pragma unroll
        for (int ks = 0; ks < 8; ++ks) {
            s16x4 lo = *(const s16x4*)(rent + ks * 8);
            s16x4 hi = *(const s16x4*)(rent + ks * 8 + 2);
            s16x8 bf = __builtin_shufflevector(lo, hi, 0, 1, 2, 3, 4, 5, 6, 7);
            acc1 = __builtin_amdgcn_mfma_f32_32x32x16_bf16(afrag[8 + ks], bf, acc1, 0, 0, 0);
        }
        int cvalid = (vmask >> nt) & 1;
        #pragma unroll
        for (int r = 0; r < 16; ++r) {
            float v = cvalid ? (acc0[r] + acc1[r]) : -INFINITY;
            vm[r] = fmaxf(vm[r], v);
        }
    }

    // Max across 32 columns within each half
    #pragma unroll
    for (int off = 1; off < 32; off <<= 1) {
        #pragma unroll
        for (int r = 0; r < 16; ++r)
            vm[r] = fmaxf(vm[r], __shfl_xor(vm[r], off, 64));
    }

    if (m31 == 0) {
        #pragma unroll
        for (int r = 0; r < 16; ++r) {
            int d = d0 + (r & 3) + 8 * (r >> 2) + 4 * half;
            float p = vm[r] + wb[d] + bb[d];
            p = (p >= 0.f) ? p : 0.1f * p;         // leaky_relu(0.1)
            out[n * DMODEL + side * EMBED + d] = tanhf(p);
        }
    }
}

// ---------------------------------------------------------------------------
// Kernel 2: support encoder (MLP + residual + LN) for 1029 rows. 4 rows/block.
// ---------------------------------------------------------------------------
#define SE_ROWS 4
__global__ __launch_bounds__(256) void support_enc_kernel(
    const float* __restrict__ qn, const float* __restrict__ sn,
    const float* __restrict__ p1W, const float* __restrict__ p1b,
    const float* __restrict__ p2W, const float* __restrict__ p2b,
    const float* __restrict__ lng, const float* __restrict__ lnb,
    float* __restrict__ query_g, float* __restrict__ sup_ln)
{
    __shared__ __align__(16) float xs[SE_ROWS][DMODEL];
    __shared__ __align__(16) float hs[SE_ROWS][DINNER];
    __shared__ __align__(16) float os[SE_ROWS][DMODEL];
    int t = threadIdx.x;
    int base_row = blockIdx.x * SE_ROWS;

    for (int r = 0; r < SE_ROWS; ++r) {
        int row = base_row + r;
        float v = 0.f;
        if (row < BQ + FEW)
            v = (row < BQ) ? qn[row * DMODEL + t] : sn[(row - BQ) * DMODEL + t];
        xs[r][t] = v;
    }
    __syncthreads();

    for (int jj = 0; jj < 2; ++jj) {
        int j = t + jj * 256;
        const float4* wrow = (const float4*)(p1W + j * DMODEL);
        float acc[SE_ROWS];
        #pragma unroll
        for (int r = 0; r < SE_ROWS; ++r) acc[r] = 0.f;
        for (int e = 0; e < DMODEL / 4; ++e) {
            float4 wv = wrow[e];
            #pragma unroll
            for (int r = 0; r < SE_ROWS; ++r) {
                float4 xv = ((const float4*)xs[r])[e];
                acc[r] += wv.x * xv.x + wv.y * xv.y + wv.z * xv.z + wv.w * xv.w;
            }
        }
        float bj = p1b[j];
        #pragma unroll
        for (int r = 0; r < SE_ROWS; ++r) hs[r][j] = fmaxf(acc[r] + bj, 0.f);
    }
    __syncthreads();

    {
        const float4* wrow = (const float4*)(p2W + t * DINNER);
        float acc[SE_ROWS];
        #pragma unroll
        for (int r = 0; r < SE_ROWS; ++r) acc[r] = 0.f;
        for (int e = 0; e < DINNER / 4; ++e) {
            float4 wv = wrow[e];
            #pragma unroll
            for (int r = 0; r < SE_ROWS; ++r) {
                float4 hv = ((const float4*)hs[r])[e];
                acc[r] += wv.x * hv.x + wv.y * hv.y + wv.z * hv.z + wv.w * hv.w;
            }
        }
        float bt = p2b[t];
        #pragma unroll
        for (int r = 0; r < SE_ROWS; ++r) os[r][t] = acc[r] + bt + xs[r][t];
    }
    __syncthreads();

    int w = t >> 6, l = t & 63;
    {
        int r = w;
        float sum = 0.f, sq = 0.f;
        for (int i = 0; i < 4; ++i) {
            float v = os[r][l + 64 * i];
            sum += v; sq += v * v;
        }
        for (int off = 32; off; off >>= 1) {
            sum += __shfl_xor(sum, off, 64);
            sq  += __shfl_xor(sq,  off, 64);
        }
        float mu  = sum * (1.f / DMODEL);
        float var = sq * (1.f / DMODEL) - mu * mu;
        float inv = rsqrtf(var + LN_EPS);
        int row = base_row + r;
        if (row < BQ + FEW) {
            float* outp = (row < BQ) ? (query_g + row * DMODEL) : (sup_ln + (row - BQ) * DMODEL);
            for (int i = 0; i < 4; ++i) {
                int dd = l + 64 * i;
                outp[dd] = (os[r][dd] - mu) * inv * lng[dd] + lnb[dd];
            }
        }
    }
}

// ---------------------------------------------------------------------------
// Kernel 3: sWp[p] = sum_e s[e] * W_hh[row(p), 256+e], with s computed inline
// as the mean of the 5 LN'd support rows. Live gate lanes only.
// ---------------------------------------------------------------------------
__global__ __launch_bounds__(256) void sWp_kernel(
    const float* __restrict__ sup_ln, const float* __restrict__ W_hh,
    float* __restrict__ sWp)
{
    int w = threadIdx.x >> 6, l = threadIdx.x & 63;
    int wave_id = blockIdx.x * 4 + w;   // 0..63
    float se[4];
    #pragma unroll
    for (int j = 0; j < 4; ++j) {
        float a = 0.f;
        for (int i = 0; i < FEW; ++i) a += sup_ln[i * DMODEL + l + 64 * j];
        se[j] = a * (1.f / FEW);
    }
    for (int i = 0; i < 16; ++i) {
        int p = wave_id * 16 + i;       // 0..1023
        int pp = p >> 8, q = p & 255;
        const float* wr = W_hh + (pp * 512 + q) * HIDN + 256;
        float part = 0.f;
        #pragma unroll
        for (int j = 0; j < 4; ++j) part += se[j] * wr[l + 64 * j];
        for (int off = 32; off; off >>= 1) part += __shfl_xor(part, off, 64);
        if (l == 0) sWp[p] = part;
    }
}

// ---------------------------------------------------------------------------
// Kernel 4: fully fused LSTM (4 steps) + final dot. The LSTM recurrence is
// per-sample independent (softmax over the single support row is identically
// 1, so r == s every step). base gates (query @ W_ih.T + biases) computed
// once; per step only h @ W_hh[:, :256].T (live lanes q<256 of each gate).
// Block = 4 samples; h rows live in LDS; c in registers.
// ---------------------------------------------------------------------------
#define LS_SAMP 4
__global__ __launch_bounds__(256) void lstm_fused_kernel(
    const float* __restrict__ query_g, const float* __restrict__ sup_ln,
    const float* __restrict__ sWp, const float* __restrict__ W_ih,
    const float* __restrict__ W_hh, const float* __restrict__ b_ih,
    const float* __restrict__ b_hh, float* __restrict__ out)
{
    __shared__ __align__(16) float xs[LS_SAMP][DMODEL];   // query rows
    __shared__ __align__(16) float hsh[LS_SAMP][DMODEL];  // h rows
    __shared__ __align__(16) float sv[DMODEL];            // s vector
    int t = threadIdx.x;
    int n0 = blockIdx.x * LS_SAMP;

    {
        float a = 0.f;
        for (int i = 0; i < FEW; ++i) a += sup_ln[i * DMODEL + t];
        sv[t] = a * (1.f / FEW);
    }
    for (int r = 0; r < LS_SAMP; ++r) xs[r][t] = query_g[(n0 + r) * DMODEL + t];
    __syncthreads();

    // base = query @ W_ih.T + b_ih + b_hh (live rows pp*512+t)
    float base[4][LS_SAMP];
    #pragma unroll
    for (int pp = 0; pp < 4; ++pp)
        #pragma unroll
        for (int r = 0; r < LS_SAMP; ++r) base[pp][r] = 0.f;
    for (int pp = 0; pp < 4; ++pp) {
        const float4* wrow = (const float4*)(W_ih + (pp * 512 + t) * DMODEL);
        for (int e = 0; e < DMODEL / 4; ++e) {
            float4 wv = wrow[e];
            #pragma unroll
            for (int r = 0; r < LS_SAMP; ++r) {
                float4 xv = ((const float4*)xs[r])[e];
                base[pp][r] += wv.x * xv.x + wv.y * xv.y + wv.z * xv.z + wv.w * xv.w;
            }
        }
    }
    float bsum[4], sw[4];
    #pragma unroll
    for (int pp = 0; pp < 4; ++pp) {
        bsum[pp] = b_ih[pp * 512 + t] + b_hh[pp * 512 + t];
        sw[pp]   = sWp[pp * 256 + t];
    }

    // step 0: h_r = 0, c = 0
    float c[LS_SAMP];
    for (int r = 0; r < LS_SAMP; ++r) {
        float gi = base[0][r] + bsum[0];
        float gf = base[1][r] + bsum[1]; (void)gf;
        float gg = base[2][r] + bsum[2];
        float go = base[3][r] + bsum[3];
        float cc = sigmoidf_(gi) * tanhf(gg);   // c0 = 0
        c[r] = cc;
        hsh[r][t] = xs[r][t] + sigmoidf_(go) * tanhf(cc);
    }
    __syncthreads();

    // steps 1..3
    for (int st = 1; st < 4; ++st) {
        float acc[4][LS_SAMP];
        #pragma unroll
        for (int pp = 0; pp < 4; ++pp)
            #pragma unroll
            for (int r = 0; r < LS_SAMP; ++r) acc[pp][r] = 0.f;
        for (int pp = 0; pp < 4; ++pp) {
            const float4* wrow = (const float4*)(W_hh + (pp * 512 + t) * HIDN); // cols 0..255
            for (int e = 0; e < DMODEL / 4; ++e) {
                float4 wv = wrow[e];
                #pragma unroll
                for (int r = 0; r < LS_SAMP; ++r) {
                    float4 hv = ((const float4*)hsh[r])[e];
                    acc[pp][r] += wv.x * hv.x + wv.y * hv.y + wv.z * hv.z + wv.w * hv.w;
                }
            }
        }
        __syncthreads();   // done reading hsh
        for (int r = 0; r < LS_SAMP; ++r) {
            float gi = base[0][r] + bsum[0] + sw[0] + acc[0][r];
            float gf = base[1][r] + bsum[1] + sw[1] + acc[1][r];
            float gg = base[2][r] + bsum[2] + sw[2] + acc[2][r];
            float go = base[3][r] + bsum[3] + sw[3] + acc[3][r];
            float cc = sigmoidf_(gf) * c[r] + sigmoidf_(gi) * tanhf(gg);
            c[r] = cc;
            hsh[r][t] = xs[r][t] + sigmoidf_(go) * tanhf(cc);
        }
        __syncthreads();
    }

    // final: out[n0+w] = dot(h[w], s); wave w handles sample w
    int w = t >> 6, l = t & 63;
    {
        float part = 0.f;
        #pragma unroll
        for (int i = 0; i < 4; ++i) {
            int e = l + 64 * i;
            part += hsh[w][e] * sv[e];
        }
        for (int off = 32; off; off >>= 1) part += __shfl_xor(part, off, 64);
        if (l == 0) out[n0 + w] = part;
    }
}

// ---------------------------------------------------------------------------
extern "C" void kernel_launch(void* const* d_in, const int* in_sizes, int n_in,
                              void* d_out, int out_size, void* d_ws, size_t ws_size,
                              hipStream_t stream)
{
    const int*   qlc  = (const int*)d_in[0];
    const int*   qrc  = (const int*)d_in[1];
    const int*   slc  = (const int*)d_in[2];
    const int*   src_ = (const int*)d_in[3];
    // d_in[4..7]: degrees — unused by the reference
    const float* emb   = (const float*)d_in[8];
    const float* gcnW  = (const float*)d_in[9];
    const float* gcnwb = (const float*)d_in[10];
    const float* gcnb  = (const float*)d_in[11];
    const float* p1W   = (const float*)d_in[12];
    const float* p1b   = (const float*)d_in[13];
    const float* p2W   = (const float*)d_in[14];
    const float* p2b   = (const float*)d_in[15];
    const float* lng   = (const float*)d_in[16];
    const float* lnb   = (const float*)d_in[17];
    const float* W_ih  = (const float*)d_in[18];
    const float* W_hh  = (const float*)d_in[19];
    const float* b_ih  = (const float*)d_in[20];
    const float* b_hh  = (const float*)d_in[21];
    float* out = (float*)d_out;

    // Workspace layout
    char* ws = (char*)d_ws;
    float* qn      = (float*)(ws + 0);         // 1048576
    float* sn      = (float*)(ws + 1048576);   // 5120
    float* query_g = (float*)(ws + 1053696);   // 1048576
    float* sup_ln  = (float*)(ws + 2102272);   // 5120
    float* sWp     = (float*)(ws + 2107392);   // 4096
    (void)ws_size; (void)in_sizes; (void)n_in; (void)out_size;

    neighbor_kernel<<<2 * BQ + 2 * FEW, 256, 0, stream>>>(
        qlc, qrc, slc, src_, emb, gcnW, gcnwb, gcnb, qn, sn);
    support_enc_kernel<<<(BQ + FEW + SE_ROWS - 1) / SE_ROWS, 256, 0, stream>>>(
        qn, sn, p1W, p1b, p2W, p2b, lng, lnb, query_g, sup_ln);
    sWp_kernel<<<16, 256, 0, stream>>>(sup_ln, W_hh, sWp);
    lstm_fused_kernel<<<BQ / LS_SAMP, 256, 0, stream>>>(
        query_g, sup_ln, sWp, W_ih, W_hh, b_ih, b_hh, out);
}

// Round 4
// 410.785 us; speedup vs baseline: 2.7683x; 1.2840x over previous
//
#include <hip/hip_runtime.h>
#include <math.h>

// Problem constants
#define EMBED   128
#define DMODEL  256   // 2*EMBED
#define DINNER  512
#define HIDN    512
#define NBK     200
#define BQ      1024
#define FEW     5
#define PAD_IDX 200000
#define LN_EPS  1e-5f
#define NTILES  7

typedef short          s16x4  __attribute__((ext_vector_type(4)));
typedef short          s16x8  __attribute__((ext_vector_type(8)));
typedef float          f32x4  __attribute__((ext_vector_type(4)));
typedef float          f32x16 __attribute__((ext_vector_type(16)));
typedef unsigned int   u32;
typedef unsigned short u16;

__device__ __forceinline__ float sigmoidf_(float x) { return 1.0f / (1.0f + expf(-x)); }

// float -> bf16 (round-to-nearest-even), raw u16
__device__ __forceinline__ u32 f2bf(float f) {
    u32 u = __builtin_bit_cast(u32, f);
    u += 0x7fffu + ((u >> 16) & 1u);
    return u >> 16;
}
__device__ __forceinline__ s16x8 pack8(float4 a, float4 b) {
    typedef u32 u32x4_ __attribute__((ext_vector_type(4)));
    u32x4_ q;
    q.x = f2bf(a.x) | (f2bf(a.y) << 16);
    q.y = f2bf(a.z) | (f2bf(a.w) << 16);
    q.z = f2bf(b.x) | (f2bf(b.y) << 16);
    q.w = f2bf(b.z) | (f2bf(b.w) << 16);
    return __builtin_bit_cast(s16x8, q);
}

// ---------------------------------------------------------------------------
// Kernel 0: convert weights to bf16 MFMA-B-fragment order.
// Frag layout for an [N x K] weight (y = x @ W^T): element (n,k) lives at
// flat = ((tile*KS + ks)*64 + lane)*8 + j, with n = tile*16 + (lane&15),
// k = ks*32 + (lane>>4)*8 + j, KS = K/32. A wave's per-(tile,ks) load is a
// consecutive 1 KB block.
// Segments: wih live rows (1024x256), whh live rows x cols[:256] (1024x256),
// p1W (512x256), p2W (256x512). Live row remap: p=pp*256+q -> row pp*512+q.
// ---------------------------------------------------------------------------
__global__ __launch_bounds__(256) void convert_weights_kernel(
    const float* __restrict__ W_ih, const float* __restrict__ W_hh,
    const float* __restrict__ p1W,  const float* __restrict__ p2W,
    u16* __restrict__ wih_bf, u16* __restrict__ whh_bf,
    u16* __restrict__ p1_bf,  u16* __restrict__ p2_bf)
{
    int gid = blockIdx.x * 256 + threadIdx.x;       // 0..98303
    const float* src; u16* dst; int local, stride, KS, liveRemap;
    if (gid < 32768)      { local = gid;          src = W_ih; dst = wih_bf; stride = 256; KS = 8;  liveRemap = 1; }
    else if (gid < 65536) { local = gid - 32768;  src = W_hh; dst = whh_bf; stride = 512; KS = 8;  liveRemap = 1; }
    else if (gid < 81920) { local = gid - 65536;  src = p1W;  dst = p1_bf;  stride = 256; KS = 8;  liveRemap = 0; }
    else                  { local = gid - 81920;  src = p2W;  dst = p2_bf;  stride = 512; KS = 16; liveRemap = 0; }
    int lane = local & 63;
    int ts   = local >> 6;
    int ks   = ts & (KS - 1);
    int tile = ts / KS;
    int n  = tile * 16 + (lane & 15);
    int kb = ks * 32 + (lane >> 4) * 8;
    int row = liveRemap ? ((n >> 8) * 512 + (n & 255)) : n;
    const float* sp = src + (size_t)row * stride + kb;
    float4 x0 = *(const float4*)sp;
    float4 x1 = *(const float4*)(sp + 4);
    *(s16x8*)(dst + (size_t)local * 8) = pack8(x0, x1);
}

// ---------------------------------------------------------------------------
// Kernel 1: neighbor encoder, MFMA bf16 32x32x16, cooperative LDS staging with
// software-pipelined gather: tile t+1's global gathers issue before tile t's
// MFMA phase, hiding the random-gather latency behind compute.
// ---------------------------------------------------------------------------
__global__ __launch_bounds__(256) void neighbor_kernel(
    const int* __restrict__ qlc, const int* __restrict__ qrc,
    const int* __restrict__ slc, const int* __restrict__ src_,
    const float* __restrict__ emb, const float* __restrict__ W,
    const float* __restrict__ wb,  const float* __restrict__ bb,
    float* __restrict__ qn, float* __restrict__ sn)
{
    int b = blockIdx.x;
    const int* conn; float* out; int n; int side;
    if (b < BQ)                { conn = qlc;  n = b;            side = 0; out = qn; }
    else if (b < 2*BQ)         { conn = qrc;  n = b - BQ;       side = 1; out = qn; }
    else if (b < 2*BQ + FEW)   { conn = slc;  n = b - 2*BQ;     side = 0; out = sn; }
    else                       { conn = src_; n = b - 2*BQ-FEW; side = 1; out = sn; }

    int t = threadIdx.x;
    int w = t >> 6, l = t & 63;
    int d0 = w * 32;
    int m31 = l & 31, half = l >> 5;

    __shared__ __align__(16) u32 bs[64 * 66];   // 16.9 KB staging

    // A-frags: afrag[ks] = W[d0+m31][ks*16 + half*8 .. +7] in bf16
    s16x8 afrag[16];
    const float* wrow = W + (d0 + m31) * DMODEL + half * 8;
    #pragma unroll
    for (int ks = 0; ks < 16; ++ks) {
        float4 x0 = *(const float4*)(wrow + ks * 16);
        float4 x1 = *(const float4*)(wrow + ks * 16 + 4);
        afrag[ks] = pack8(x0, x1);
    }

    // Column-validity bitmask for this lane's column m31
    const int* crow = conn + n * NBK * 2;
    u32 vmask = 0;
    #pragma unroll
    for (int nt = 0; nt < NTILES; ++nt) {
        int krow = nt * 32 + m31;
        if (krow < NBK) {
            int rel = crow[2 * krow], ent = crow[2 * krow + 1];
            if (rel != PAD_IDX && ent != PAD_IDX) vmask |= (1u << nt);
        }
    }

    // Gather mapping: thread t -> row gr (0..63), quarter gq (32 floats)
    int gr = t >> 2;
    int gq = t & 3;
    int g_is_ent = (gr >= 32);
    int g_m = gr & 31;

    // Per-thread gather source row per tile
    int srcrow[NTILES];
    #pragma unroll
    for (int nt = 0; nt < NTILES; ++nt) {
        int krow = nt * 32 + g_m;
        int rel = PAD_IDX, ent = PAD_IDX;
        if (krow < NBK) { rel = crow[2 * krow]; ent = crow[2 * krow + 1]; }
        int gvalid = (rel != PAD_IDX) && (ent != PAD_IDX);
        srcrow[nt] = gvalid ? (g_is_ent ? ent : rel) : PAD_IDX;  // PAD row = zeros
    }

    // Valid-tile list (block-uniform: vmask distribution identical per wave)
    int tl[NTILES]; int ntl = 0;
    #pragma unroll
    for (int nt = 0; nt < NTILES; ++nt)
        if (__any((int)((vmask >> nt) & 1u))) tl[ntl++] = nt;

    float vm[16];
    #pragma unroll
    for (int r = 0; r < 16; ++r) vm[r] = -INFINITY;

    u32* dst = bs + gr * 66 + gq * 16;
    const u32* rrel = bs + m31 * 66 + half * 4;
    const u32* rent = bs + (32 + m31) * 66 + half * 4;

    float4 f[8];
    if (ntl > 0) {
        const float4* gp = (const float4*)(emb + (size_t)srcrow[tl[0]] * EMBED + gq * 32);
        #pragma unroll
        for (int i = 0; i < 8; ++i) f[i] = gp[i];
    }

    for (int i = 0; i < ntl; ++i) {
        int nt = tl[i];
        __syncthreads();   // previous tile's LDS reads complete
        #pragma unroll
        for (int j = 0; j < 8; ++j) {
            dst[2 * j]     = f2bf(f[j].x) | (f2bf(f[j].y) << 16);
            dst[2 * j + 1] = f2bf(f[j].z) | (f2bf(f[j].w) << 16);
        }
        __syncthreads();   // staged tile visible

        // prefetch next tile's rows (latency hidden behind MFMA below)
        float4 f2[8];
        if (i + 1 < ntl) {
            const float4* gp = (const float4*)(emb + (size_t)srcrow[tl[i + 1]] * EMBED + gq * 32);
            #pragma unroll
            for (int j = 0; j < 8; ++j) f2[j] = gp[j];
        }

        // MFMA from LDS
        f32x16 acc0 = {0.f,0.f,0.f,0.f,0.f,0.f,0.f,0.f,0.f,0.f,0.f,0.f,0.f,0.f,0.f,0.f};
        f32x16 acc1 = acc0;
        #pragma unroll
        for (int ks = 0; ks < 8; ++ks) {
            s16x4 lo = *(const s16x4*)(rrel + ks * 8);
            s16x4 hi = *(const s16x4*)(rrel + ks * 8 + 2);
            s16x8 bf = __builtin_shufflevector(lo, hi, 0, 1, 2, 3, 4, 5, 6, 7);
            acc0 = __builtin_amdgcn_mfma_f32_32x32x16_bf16(afrag[ks], bf, acc0, 0, 0, 0);
        }
        #pragma unroll
        for (int ks = 0; ks < 8; ++ks) {
            s16x4 lo = *(const s16x4*)(rent + ks * 8);
            s16x4 hi = *(const s16x4*)(rent + ks * 8 + 2);
            s16x8 bf = __builtin_shufflevector(lo, hi, 0, 1, 2, 3, 4, 5, 6, 7);
            acc1 = __builtin_amdgcn_mfma_f32_32x32x16_bf16(afrag[8 + ks], bf, acc1, 0, 0, 0);
        }
        int cvalid = (vmask >> nt) & 1;
        #pragma unroll
        for (int r = 0; r < 16; ++r) {
            float v = cvalid ? (acc0[r] + acc1[r]) : -INFINITY;
            vm[r] = fmaxf(vm[r], v);
        }
        #pragma unroll
        for (int j = 0; j < 8; ++j) f[j] = f2[j];
    }

    // Max across 32 columns within each half
    #pragma unroll
    for (int off = 1; off < 32; off <<= 1) {
        #pragma unroll
        for (int r = 0; r < 16; ++r)
            vm[r] = fmaxf(vm[r], __shfl_xor(vm[r], off, 64));
    }

    if (m31 == 0) {
        #pragma unroll
        for (int r = 0; r < 16; ++r) {
            int d = d0 + (r & 3) + 8 * (r >> 2) + 4 * half;
            float p = vm[r] + wb[d] + bb[d];
            p = (p >= 0.f) ? p : 0.1f * p;         // leaky_relu(0.1)
            out[n * DMODEL + side * EMBED + d] = tanhf(p);
        }
    }
}

// ---------------------------------------------------------------------------
// Kernel 2: support encoder via MFMA 16x16x32 bf16. 16 rows per block.
// GEMM1 (256->512, relu) -> LDS transpose -> GEMM2 (512->256, +bias+residual)
// -> LayerNorm. Waves split N.
// ---------------------------------------------------------------------------
__global__ __launch_bounds__(256) void support_enc_kernel(
    const float* __restrict__ qn, const float* __restrict__ sn,
    const u16* __restrict__ p1_bf, const float* __restrict__ p1b,
    const u16* __restrict__ p2_bf, const float* __restrict__ p2b,
    const float* __restrict__ lng, const float* __restrict__ lnb,
    float* __restrict__ query_g, float* __restrict__ sup_ln)
{
    __shared__ __align__(16) float xs[16][260];
    __shared__ __align__(16) float hsd[16][516];
    __shared__ __align__(16) float os[16][260];
    int t = threadIdx.x;
    int w = t >> 6, l = t & 63;
    int r0 = blockIdx.x * 16;

    for (int r = 0; r < 16; ++r) {
        int row = r0 + r;
        float v = 0.f;
        if (row < BQ + FEW)
            v = (row < BQ) ? qn[row * DMODEL + t] : sn[(row - BQ) * DMODEL + t];
        xs[r][t] = v;
    }
    __syncthreads();

    int am = l & 15, ak = (l >> 4) * 8;

    // A1 frags (x rows, bf16)
    s16x8 a1[8];
    #pragma unroll
    for (int ks = 0; ks < 8; ++ks) {
        float4 x0 = *(const float4*)&xs[am][ks * 32 + ak];
        float4 x1 = *(const float4*)&xs[am][ks * 32 + ak + 4];
        a1[ks] = pack8(x0, x1);
    }

    // GEMM1: N=512 -> 32 n-tiles, wave w owns tiles w*8..w*8+7
    #pragma unroll
    for (int j = 0; j < 8; ++j) {
        int nt = w * 8 + j;
        f32x4 acc = {0.f, 0.f, 0.f, 0.f};
        const u16* bp = p1_bf + (size_t)nt * 4096 + l * 8;
        #pragma unroll
        for (int ks = 0; ks < 8; ++ks) {
            s16x8 bf = *(const s16x8*)(bp + ks * 512);
            acc = __builtin_amdgcn_mfma_f32_16x16x32_bf16(a1[ks], bf, acc, 0, 0, 0);
        }
        int nn = nt * 16 + (l & 15);
        float bj = p1b[nn];
        #pragma unroll
        for (int reg = 0; reg < 4; ++reg) {
            int m = (l >> 4) * 4 + reg;
            hsd[m][nn] = fmaxf(acc[reg] + bj, 0.f);
        }
    }
    __syncthreads();

    // A2 frags (h rows, K=512 -> 16 ksteps)
    s16x8 a2[16];
    #pragma unroll
    for (int ks = 0; ks < 16; ++ks) {
        float4 x0 = *(const float4*)&hsd[am][ks * 32 + ak];
        float4 x1 = *(const float4*)&hsd[am][ks * 32 + ak + 4];
        a2[ks] = pack8(x0, x1);
    }

    // GEMM2: N=256 -> 16 n-tiles, wave w owns tiles w*4..w*4+3 (KS=16)
    #pragma unroll
    for (int j = 0; j < 4; ++j) {
        int nt = w * 4 + j;
        f32x4 acc = {0.f, 0.f, 0.f, 0.f};
        const u16* bp = p2_bf + (size_t)nt * 8192 + l * 8;
        #pragma unroll
        for (int ks = 0; ks < 16; ++ks) {
            s16x8 bf = *(const s16x8*)(bp + ks * 512);
            acc = __builtin_amdgcn_mfma_f32_16x16x32_bf16(a2[ks], bf, acc, 0, 0, 0);
        }
        int nn = nt * 16 + (l & 15);
        float bj = p2b[nn];
        #pragma unroll
        for (int reg = 0; reg < 4; ++reg) {
            int m = (l >> 4) * 4 + reg;
            os[m][nn] = acc[reg] + bj + xs[m][nn];
        }
    }
    __syncthreads();

    // LayerNorm: wave w rows w*4..w*4+3
    for (int j = 0; j < 4; ++j) {
        int m = w * 4 + j;
        float sum = 0.f, sq = 0.f;
        #pragma unroll
        for (int i = 0; i < 4; ++i) {
            float v = os[m][l + 64 * i];
            sum += v; sq += v * v;
        }
        for (int off = 32; off; off >>= 1) {
            sum += __shfl_xor(sum, off, 64);
            sq  += __shfl_xor(sq,  off, 64);
        }
        float mu  = sum * (1.f / DMODEL);
        float var = sq * (1.f / DMODEL) - mu * mu;
        float inv = rsqrtf(var + LN_EPS);
        int row = r0 + m;
        if (row < BQ + FEW) {
            float* outp = (row < BQ) ? (query_g + row * DMODEL) : (sup_ln + (row - BQ) * DMODEL);
            #pragma unroll
            for (int i = 0; i < 4; ++i) {
                int dd = l + 64 * i;
                outp[dd] = (os[m][dd] - mu) * inv * lng[dd] + lnb[dd];
            }
        }
    }
}

// ---------------------------------------------------------------------------
// Kernel 3: sWp[p] = sum_e s[e] * W_hh[row(p), 256+e]; s = mean of LN'd
// support rows. 64 blocks x 4 waves, 4 outputs per wave.
// ---------------------------------------------------------------------------
__global__ __launch_bounds__(256) void sWp_kernel(
    const float* __restrict__ sup_ln, const float* __restrict__ W_hh,
    float* __restrict__ sWp)
{
    int w = threadIdx.x >> 6, l = threadIdx.x & 63;
    int wave_id = blockIdx.x * 4 + w;   // 0..255
    float se[4];
    #pragma unroll
    for (int j = 0; j < 4; ++j) {
        float a = 0.f;
        for (int i = 0; i < FEW; ++i) a += sup_ln[i * DMODEL + l + 64 * j];
        se[j] = a * (1.f / FEW);
    }
    for (int i = 0; i < 4; ++i) {
        int p = wave_id * 4 + i;        // 0..1023
        int pp = p >> 8, q = p & 255;
        const float* wr = W_hh + (size_t)(pp * 512 + q) * HIDN + 256;
        float part = 0.f;
        #pragma unroll
        for (int j = 0; j < 4; ++j) part += se[j] * wr[l + 64 * j];
        for (int off = 32; off; off >>= 1) part += __shfl_xor(part, off, 64);
        if (l == 0) sWp[p] = part;
    }
}

// ---------------------------------------------------------------------------
// Kernel 4: fused LSTM (4 steps) + final dot, MFMA 16x16x32 bf16.
// Block = 16 samples, 4 waves; wave w owns gate columns q in [w*64,(w+1)*64):
// live-row n-tiles tp = pp*16 + w*4 + qt for gate pp, sub-tile qt.
// base (query@W_ih^T + biases [+ sWp after step0]) in registers as MFMA C;
// c state in registers; h transposes through LDS each step.
// ---------------------------------------------------------------------------
__global__ __launch_bounds__(256) void lstm_mfma_kernel(
    const float* __restrict__ query_g, const float* __restrict__ sup_ln,
    const float* __restrict__ sWp, const u16* __restrict__ wih_bf,
    const u16* __restrict__ whh_bf, const float* __restrict__ b_ih,
    const float* __restrict__ b_hh, float* __restrict__ out)
{
    __shared__ __align__(16) float qs[16][260];
    __shared__ __align__(16) float hs[16][260];
    __shared__ float sv[DMODEL];
    int t = threadIdx.x;
    int w = t >> 6, l = t & 63;
    int n0 = blockIdx.x * 16;

    {
        float a = 0.f;
        for (int i = 0; i < FEW; ++i) a += sup_ln[i * DMODEL + t];
        sv[t] = a * (1.f / FEW);
    }
    for (int r = 0; r < 16; ++r) qs[r][t] = query_g[(size_t)(n0 + r) * DMODEL + t];
    __syncthreads();

    int am = l & 15, ak = (l >> 4) * 8;

    // A-frags from query
    s16x8 af[8];
    #pragma unroll
    for (int ks = 0; ks < 8; ++ks) {
        float4 x0 = *(const float4*)&qs[am][ks * 32 + ak];
        float4 x1 = *(const float4*)&qs[am][ks * 32 + ak + 4];
        af[ks] = pack8(x0, x1);
    }

    // base GEMM: query @ W_ih_live^T
    f32x4 base[4][4];
    #pragma unroll
    for (int pp = 0; pp < 4; ++pp) {
        #pragma unroll
        for (int qt = 0; qt < 4; ++qt) {
            int tp = pp * 16 + w * 4 + qt;
            f32x4 acc = {0.f, 0.f, 0.f, 0.f};
            const u16* bp = wih_bf + (size_t)tp * 4096 + l * 8;
            #pragma unroll
            for (int ks = 0; ks < 8; ++ks) {
                s16x8 bf = *(const s16x8*)(bp + ks * 512);
                acc = __builtin_amdgcn_mfma_f32_16x16x32_bf16(af[ks], bf, acc, 0, 0, 0);
            }
            base[pp][qt] = acc;
        }
    }
    // + biases (per n position, same for all 4 m-regs)
    #pragma unroll
    for (int pp = 0; pp < 4; ++pp) {
        #pragma unroll
        for (int qt = 0; qt < 4; ++qt) {
            int q = w * 64 + qt * 16 + (l & 15);
            float bsv = b_ih[pp * 512 + q] + b_hh[pp * 512 + q];
            base[pp][qt].x += bsv; base[pp][qt].y += bsv;
            base[pp][qt].z += bsv; base[pp][qt].w += bsv;
        }
    }

    // step 0 (h_r = 0, c = 0)
    float c[4][4];   // [qt][reg]
    #pragma unroll
    for (int qt = 0; qt < 4; ++qt) {
        int q = w * 64 + qt * 16 + (l & 15);
        #pragma unroll
        for (int reg = 0; reg < 4; ++reg) {
            int m = (l >> 4) * 4 + reg;
            float gi = base[0][qt][reg];
            float gg = base[2][qt][reg];
            float go = base[3][qt][reg];
            float cc = sigmoidf_(gi) * tanhf(gg);
            c[qt][reg] = cc;
            hs[m][q] = qs[m][q] + sigmoidf_(go) * tanhf(cc);
        }
    }
    // fold sWp into base (applies to steps 1..3 only)
    #pragma unroll
    for (int pp = 0; pp < 4; ++pp) {
        #pragma unroll
        for (int qt = 0; qt < 4; ++qt) {
            int q = w * 64 + qt * 16 + (l & 15);
            float sw = sWp[pp * 256 + q];
            base[pp][qt].x += sw; base[pp][qt].y += sw;
            base[pp][qt].z += sw; base[pp][qt].w += sw;
        }
    }
    __syncthreads();

    // steps 1..3
    for (int st = 1; st < 4; ++st) {
        // A-frags from h (fp32 LDS -> bf16)
        #pragma unroll
        for (int ks = 0; ks < 8; ++ks) {
            float4 x0 = *(const float4*)&hs[am][ks * 32 + ak];
            float4 x1 = *(const float4*)&hs[am][ks * 32 + ak + 4];
            af[ks] = pack8(x0, x1);
        }
        __syncthreads();   // all reads done before epilogue writes

        f32x4 gacc[4][4];
        #pragma unroll
        for (int pp = 0; pp < 4; ++pp) {
            #pragma unroll
            for (int qt = 0; qt < 4; ++qt) {
                int tp = pp * 16 + w * 4 + qt;
                f32x4 acc = base[pp][qt];   // MFMA C-init carries base+bias+sw
                const u16* bp = whh_bf + (size_t)tp * 4096 + l * 8;
                #pragma unroll
                for (int ks = 0; ks < 8; ++ks) {
                    s16x8 bf = *(const s16x8*)(bp + ks * 512);
                    acc = __builtin_amdgcn_mfma_f32_16x16x32_bf16(af[ks], bf, acc, 0, 0, 0);
                }
                gacc[pp][qt] = acc;
            }
        }
        #pragma unroll
        for (int qt = 0; qt < 4; ++qt) {
            int q = w * 64 + qt * 16 + (l & 15);
            #pragma unroll
            for (int reg = 0; reg < 4; ++reg) {
                int m = (l >> 4) * 4 + reg;
                float gi = gacc[0][qt][reg];
                float gf = gacc[1][qt][reg];
                float gg = gacc[2][qt][reg];
                float go = gacc[3][qt][reg];
                float cc = sigmoidf_(gf) * c[qt][reg] + sigmoidf_(gi) * tanhf(gg);
                c[qt][reg] = cc;
                hs[m][q] = qs[m][q] + sigmoidf_(go) * tanhf(cc);
            }
        }
        __syncthreads();   // writes visible before next step's reads
    }

    // final: out[n0+m] = dot(h3[m], s); wave w handles samples w*4..w*4+3
    for (int j = 0; j < 4; ++j) {
        int m = w * 4 + j;
        float part = 0.f;
        #pragma unroll
        for (int i = 0; i < 4; ++i) {
            int e = l + 64 * i;
            part += hs[m][e] * sv[e];
        }
        for (int off = 32; off; off >>= 1) part += __shfl_xor(part, off, 64);
        if (l == 0) out[n0 + m] = part;
    }
}

// ---------------------------------------------------------------------------
extern "C" void kernel_launch(void* const* d_in, const int* in_sizes, int n_in,
                              void* d_out, int out_size, void* d_ws, size_t ws_size,
                              hipStream_t stream)
{
    const int*   qlc  = (const int*)d_in[0];
    const int*   qrc  = (const int*)d_in[1];
    const int*   slc  = (const int*)d_in[2];
    const int*   src_ = (const int*)d_in[3];
    // d_in[4..7]: degrees — unused by the reference
    const float* emb   = (const float*)d_in[8];
    const float* gcnW  = (const float*)d_in[9];
    const float* gcnwb = (const float*)d_in[10];
    const float* gcnb  = (const float*)d_in[11];
    const float* p1W   = (const float*)d_in[12];
    const float* p1b   = (const float*)d_in[13];
    const float* p2W   = (const float*)d_in[14];
    const float* p2b   = (const float*)d_in[15];
    const float* lng   = (const float*)d_in[16];
    const float* lnb   = (const float*)d_in[17];
    const float* W_ih  = (const float*)d_in[18];
    const float* W_hh  = (const float*)d_in[19];
    const float* b_ih  = (const float*)d_in[20];
    const float* b_hh  = (const float*)d_in[21];
    float* out = (float*)d_out;

    // Workspace layout
    char* ws = (char*)d_ws;
    float* qn      = (float*)(ws + 0);         // 1048576
    float* sn      = (float*)(ws + 1048576);   // 5120
    float* query_g = (float*)(ws + 1053696);   // 1048576
    float* sup_ln  = (float*)(ws + 2102272);   // 5120
    float* sWp     = (float*)(ws + 2107392);   // 4096
    u16*   wih_bf  = (u16*)(ws + 2111488);     // 524288
    u16*   whh_bf  = (u16*)(ws + 2635776);     // 524288
    u16*   p1_bf   = (u16*)(ws + 3160064);     // 262144
    u16*   p2_bf   = (u16*)(ws + 3422208);     // 262144  -> total 3684352
    (void)ws_size; (void)in_sizes; (void)n_in; (void)out_size;

    convert_weights_kernel<<<384, 256, 0, stream>>>(
        W_ih, W_hh, p1W, p2W, wih_bf, whh_bf, p1_bf, p2_bf);
    neighbor_kernel<<<2 * BQ + 2 * FEW, 256, 0, stream>>>(
        qlc, qrc, slc, src_, emb, gcnW, gcnwb, gcnb, qn, sn);
    support_enc_kernel<<<(BQ + FEW + 15) / 16, 256, 0, stream>>>(
        qn, sn, p1_bf, p1b, p2_bf, p2b, lng, lnb, query_g, sup_ln);
    sWp_kernel<<<64, 256, 0, stream>>>(sup_ln, W_hh, sWp);
    lstm_mfma_kernel<<<BQ / 16, 256, 0, stream>>>(
        query_g, sup_ln, sWp, wih_bf, whh_bf, b_ih, b_hh, out);
}

// Round 5
// 404.439 us; speedup vs baseline: 2.8118x; 1.0157x over previous
//
#include <hip/hip_runtime.h>
#include <math.h>

// Problem constants
#define EMBED   128
#define DMODEL  256   // 2*EMBED
#define DINNER  512
#define HIDN    512
#define NBK     200
#define BQ      1024
#define FEW     5
#define PAD_IDX 200000
#define LN_EPS  1e-5f
#define NTILES  7

#define EMB_ELEMS 25600128   // 200001 * 128
#define EMB_THREADS (EMB_ELEMS / 8)
#define EMB_BLOCKS ((EMB_THREADS + 255) / 256)

typedef short          s16x8  __attribute__((ext_vector_type(8)));
typedef float          f32x4  __attribute__((ext_vector_type(4)));
typedef float          f32x16 __attribute__((ext_vector_type(16)));
typedef unsigned int   u32;
typedef unsigned short u16;

__device__ __forceinline__ float sigmoidf_(float x) { return 1.0f / (1.0f + expf(-x)); }

// float -> bf16 (round-to-nearest-even), raw u16
__device__ __forceinline__ u32 f2bf(float f) {
    u32 u = __builtin_bit_cast(u32, f);
    u += 0x7fffu + ((u >> 16) & 1u);
    return u >> 16;
}
__device__ __forceinline__ s16x8 pack8(float4 a, float4 b) {
    typedef u32 u32x4_ __attribute__((ext_vector_type(4)));
    u32x4_ q;
    q.x = f2bf(a.x) | (f2bf(a.y) << 16);
    q.y = f2bf(a.z) | (f2bf(a.w) << 16);
    q.z = f2bf(b.x) | (f2bf(b.y) << 16);
    q.w = f2bf(b.z) | (f2bf(b.w) << 16);
    return __builtin_bit_cast(s16x8, q);
}

// ---------------------------------------------------------------------------
// Kernel 0: one conversion kernel for everything.
// Blocks [0,384): weights -> bf16 MFMA-B-fragment order (wih/whh live rows,
// p1W, p2W). Blocks [384, 384+embN): emb (200001x128 fp32) -> emb_bf (bf16).
// Frag layout for [N x K] weight (y = x @ W^T): element (n,k) at
// flat = ((tile*KS + ks)*64 + lane)*8 + j, n = tile*16 + (lane&15),
// k = ks*32 + (lane>>4)*8 + j, KS = K/32.
// ---------------------------------------------------------------------------
__global__ __launch_bounds__(256) void convert_all_kernel(
    const float* __restrict__ W_ih, const float* __restrict__ W_hh,
    const float* __restrict__ p1W,  const float* __restrict__ p2W,
    const float* __restrict__ emb,
    u16* __restrict__ wih_bf, u16* __restrict__ whh_bf,
    u16* __restrict__ p1_bf,  u16* __restrict__ p2_bf,
    u16* __restrict__ emb_bf)
{
    int bid = blockIdx.x;
    if (bid >= 384) {
        // emb conversion: 8 elems per thread
        size_t gid = (size_t)(bid - 384) * 256 + threadIdx.x;
        if (gid < EMB_THREADS) {
            size_t base = gid * 8;
            float4 x0 = *(const float4*)(emb + base);
            float4 x1 = *(const float4*)(emb + base + 4);
            *(s16x8*)(emb_bf + base) = pack8(x0, x1);
        }
        return;
    }
    int gid = bid * 256 + threadIdx.x;              // 0..98303
    const float* src; u16* dst; int local, stride, KS, liveRemap;
    if (gid < 32768)      { local = gid;          src = W_ih; dst = wih_bf; stride = 256; KS = 8;  liveRemap = 1; }
    else if (gid < 65536) { local = gid - 32768;  src = W_hh; dst = whh_bf; stride = 512; KS = 8;  liveRemap = 1; }
    else if (gid < 81920) { local = gid - 65536;  src = p1W;  dst = p1_bf;  stride = 256; KS = 8;  liveRemap = 0; }
    else                  { local = gid - 81920;  src = p2W;  dst = p2_bf;  stride = 512; KS = 16; liveRemap = 0; }
    int lane = local & 63;
    int ts   = local >> 6;
    int ks   = ts & (KS - 1);
    int tile = ts / KS;
    int n  = tile * 16 + (lane & 15);
    int kb = ks * 32 + (lane >> 4) * 8;
    int row = liveRemap ? ((n >> 8) * 512 + (n & 255)) : n;
    const float* sp = src + (size_t)row * stride + kb;
    float4 x0 = *(const float4*)sp;
    float4 x1 = *(const float4*)(sp + 4);
    *(s16x8*)(dst + (size_t)local * 8) = pack8(x0, x1);
}

// ---------------------------------------------------------------------------
// Kernel 1: neighbor encoder, MFMA bf16 32x32x16, DIRECT fragment gather:
// no LDS, no barriers. Each lane's B-frag is 8 consecutive elements of one
// gathered embedding row, loaded straight from global (bf16 table if BF,
// else fp32 + in-register convert). The 4 waves of a block read the same
// tile rows -> L1/L2 absorb the redundancy. Waves free-run; 16 independent
// loads in flight per tile hide the gather latency.
// Epilogue: masked max over k-cols of raw dots, then bias+leaky+tanh.
// ---------------------------------------------------------------------------
template<bool BF>
__global__ __launch_bounds__(256) void neighbor_kernel(
    const int* __restrict__ qlc, const int* __restrict__ qrc,
    const int* __restrict__ slc, const int* __restrict__ src_,
    const float* __restrict__ emb, const u16* __restrict__ emb_bf,
    const float* __restrict__ W,
    const float* __restrict__ wb,  const float* __restrict__ bb,
    float* __restrict__ qn, float* __restrict__ sn)
{
    int b = blockIdx.x;
    const int* conn; float* out; int n; int side;
    if (b < BQ)                { conn = qlc;  n = b;            side = 0; out = qn; }
    else if (b < 2*BQ)         { conn = qrc;  n = b - BQ;       side = 1; out = qn; }
    else if (b < 2*BQ + FEW)   { conn = slc;  n = b - 2*BQ;     side = 0; out = sn; }
    else                       { conn = src_; n = b - 2*BQ-FEW; side = 1; out = sn; }

    int t = threadIdx.x;
    int w = t >> 6, l = t & 63;
    int d0 = w * 32;
    int m31 = l & 31, half = l >> 5;

    // A-frags: afrag[ks] = W[d0+m31][ks*16 + half*8 .. +7] in bf16
    s16x8 afrag[16];
    const float* wrow = W + (d0 + m31) * DMODEL + half * 8;
    #pragma unroll
    for (int ks = 0; ks < 16; ++ks) {
        float4 x0 = *(const float4*)(wrow + ks * 16);
        float4 x1 = *(const float4*)(wrow + ks * 16 + 4);
        afrag[ks] = pack8(x0, x1);
    }

    // Per-column (m31) indices + validity per tile
    const int2* crow = (const int2*)(conn + n * NBK * 2);
    int srel[NTILES], sent[NTILES];
    u32 vmask = 0;
    #pragma unroll
    for (int nt = 0; nt < NTILES; ++nt) {
        int krow = nt * 32 + m31;
        int rel = PAD_IDX, ent = PAD_IDX;
        if (krow < NBK) { int2 re = crow[krow]; rel = re.x; ent = re.y; }
        int v = (rel != PAD_IDX) && (ent != PAD_IDX);
        if (v) vmask |= (1u << nt);
        srel[nt] = v ? rel : PAD_IDX;   // PAD row of emb is zeros
        sent[nt] = v ? ent : PAD_IDX;
    }

    float vm[16];
    #pragma unroll
    for (int r = 0; r < 16; ++r) vm[r] = -INFINITY;

    for (int nt = 0; nt < NTILES; ++nt) {
        if (!__any((int)((vmask >> nt) & 1u))) continue;   // wave-level skip

        s16x8 bfr[16];
        if (BF) {
            const u16* pr = emb_bf + (size_t)srel[nt] * EMBED + half * 8;
            const u16* pe = emb_bf + (size_t)sent[nt] * EMBED + half * 8;
            #pragma unroll
            for (int ks = 0; ks < 8; ++ks) bfr[ks]     = *(const s16x8*)(pr + ks * 16);
            #pragma unroll
            for (int ks = 0; ks < 8; ++ks) bfr[8 + ks] = *(const s16x8*)(pe + ks * 16);
        } else {
            const float* pr = emb + (size_t)srel[nt] * EMBED + half * 8;
            const float* pe = emb + (size_t)sent[nt] * EMBED + half * 8;
            #pragma unroll
            for (int ks = 0; ks < 8; ++ks)
                bfr[ks] = pack8(*(const float4*)(pr + ks * 16), *(const float4*)(pr + ks * 16 + 4));
            #pragma unroll
            for (int ks = 0; ks < 8; ++ks)
                bfr[8 + ks] = pack8(*(const float4*)(pe + ks * 16), *(const float4*)(pe + ks * 16 + 4));
        }

        f32x16 acc = {0.f,0.f,0.f,0.f,0.f,0.f,0.f,0.f,0.f,0.f,0.f,0.f,0.f,0.f,0.f,0.f};
        #pragma unroll
        for (int j = 0; j < 16; ++j)
            acc = __builtin_amdgcn_mfma_f32_32x32x16_bf16(afrag[j], bfr[j], acc, 0, 0, 0);

        int cv = (vmask >> nt) & 1;
        #pragma unroll
        for (int r = 0; r < 16; ++r) {
            float v = cv ? acc[r] : -INFINITY;
            vm[r] = fmaxf(vm[r], v);
        }
    }

    // Max across 32 columns within each half-wave
    #pragma unroll
    for (int off = 1; off < 32; off <<= 1) {
        #pragma unroll
        for (int r = 0; r < 16; ++r)
            vm[r] = fmaxf(vm[r], __shfl_xor(vm[r], off, 64));
    }

    if (m31 == 0) {
        #pragma unroll
        for (int r = 0; r < 16; ++r) {
            int d = d0 + (r & 3) + 8 * (r >> 2) + 4 * half;
            float p = vm[r] + wb[d] + bb[d];
            p = (p >= 0.f) ? p : 0.1f * p;         // leaky_relu(0.1)
            out[n * DMODEL + side * EMBED + d] = tanhf(p);
        }
    }
}

// ---------------------------------------------------------------------------
// Kernel 2: support encoder via MFMA 16x16x32 bf16. 16 rows/block, 512 thr
// (8 waves). GEMM1 (256->512, relu) -> LDS -> GEMM2 (512->256, +bias+res)
// -> LayerNorm.
// ---------------------------------------------------------------------------
__global__ __launch_bounds__(512) void support_enc_kernel(
    const float* __restrict__ qn, const float* __restrict__ sn,
    const u16* __restrict__ p1_bf, const float* __restrict__ p1b,
    const u16* __restrict__ p2_bf, const float* __restrict__ p2b,
    const float* __restrict__ lng, const float* __restrict__ lnb,
    float* __restrict__ query_g, float* __restrict__ sup_ln)
{
    __shared__ __align__(16) float xs[16][260];
    __shared__ __align__(16) float hsd[16][516];
    __shared__ __align__(16) float os[16][260];
    int t = threadIdx.x;
    int w = t >> 6, l = t & 63;
    int r0 = blockIdx.x * 16;

    #pragma unroll
    for (int j = 0; j < 8; ++j) {
        int idx = j * 512 + t;              // 0..4095
        int r = idx >> 8, cc = idx & 255;
        int row = r0 + r;
        float v = 0.f;
        if (row < BQ + FEW)
            v = (row < BQ) ? qn[(size_t)row * DMODEL + cc] : sn[(size_t)(row - BQ) * DMODEL + cc];
        xs[r][cc] = v;
    }
    __syncthreads();

    int am = l & 15, ak = (l >> 4) * 8;

    // A1 frags (x rows)
    s16x8 a1[8];
    #pragma unroll
    for (int ks = 0; ks < 8; ++ks) {
        float4 x0 = *(const float4*)&xs[am][ks * 32 + ak];
        float4 x1 = *(const float4*)&xs[am][ks * 32 + ak + 4];
        a1[ks] = pack8(x0, x1);
    }

    // GEMM1: 32 n-tiles, wave w owns 4w..4w+3
    #pragma unroll
    for (int j = 0; j < 4; ++j) {
        int nt = w * 4 + j;
        f32x4 acc = {0.f, 0.f, 0.f, 0.f};
        const u16* bp = p1_bf + (size_t)nt * 4096 + l * 8;
        #pragma unroll
        for (int ks = 0; ks < 8; ++ks) {
            s16x8 bf = *(const s16x8*)(bp + ks * 512);
            acc = __builtin_amdgcn_mfma_f32_16x16x32_bf16(a1[ks], bf, acc, 0, 0, 0);
        }
        int nn = nt * 16 + (l & 15);
        float bj = p1b[nn];
        #pragma unroll
        for (int reg = 0; reg < 4; ++reg) {
            int m = (l >> 4) * 4 + reg;
            hsd[m][nn] = fmaxf(acc[reg] + bj, 0.f);
        }
    }
    __syncthreads();

    // A2 frags (h rows, K=512)
    s16x8 a2[16];
    #pragma unroll
    for (int ks = 0; ks < 16; ++ks) {
        float4 x0 = *(const float4*)&hsd[am][ks * 32 + ak];
        float4 x1 = *(const float4*)&hsd[am][ks * 32 + ak + 4];
        a2[ks] = pack8(x0, x1);
    }

    // GEMM2: 16 n-tiles, wave w owns 2w, 2w+1 (KS=16)
    #pragma unroll
    for (int j = 0; j < 2; ++j) {
        int nt = w * 2 + j;
        f32x4 acc = {0.f, 0.f, 0.f, 0.f};
        const u16* bp = p2_bf + (size_t)nt * 8192 + l * 8;
        #pragma unroll
        for (int ks = 0; ks < 16; ++ks) {
            s16x8 bf = *(const s16x8*)(bp + ks * 512);
            acc = __builtin_amdgcn_mfma_f32_16x16x32_bf16(a2[ks], bf, acc, 0, 0, 0);
        }
        int nn = nt * 16 + (l & 15);
        float bj = p2b[nn];
        #pragma unroll
        for (int reg = 0; reg < 4; ++reg) {
            int m = (l >> 4) * 4 + reg;
            os[m][nn] = acc[reg] + bj + xs[m][nn];
        }
    }
    __syncthreads();

    // LayerNorm: wave w rows 2w, 2w+1
    for (int j = 0; j < 2; ++j) {
        int m = w * 2 + j;
        float sum = 0.f, sq = 0.f;
        #pragma unroll
        for (int i = 0; i < 4; ++i) {
            float v = os[m][l + 64 * i];
            sum += v; sq += v * v;
        }
        for (int off = 32; off; off >>= 1) {
            sum += __shfl_xor(sum, off, 64);
            sq  += __shfl_xor(sq,  off, 64);
        }
        float mu  = sum * (1.f / DMODEL);
        float var = sq * (1.f / DMODEL) - mu * mu;
        float inv = rsqrtf(var + LN_EPS);
        int row = r0 + m;
        if (row < BQ + FEW) {
            float* outp = (row < BQ) ? (query_g + (size_t)row * DMODEL) : (sup_ln + (size_t)(row - BQ) * DMODEL);
            #pragma unroll
            for (int i = 0; i < 4; ++i) {
                int dd = l + 64 * i;
                outp[dd] = (os[m][dd] - mu) * inv * lng[dd] + lnb[dd];
            }
        }
    }
}

// ---------------------------------------------------------------------------
// Kernel 3: sWp[p] = sum_e s[e] * W_hh[row(p), 256+e]; s = mean of LN'd
// support rows. 64 blocks x 4 waves, 4 outputs per wave.
// ---------------------------------------------------------------------------
__global__ __launch_bounds__(256) void sWp_kernel(
    const float* __restrict__ sup_ln, const float* __restrict__ W_hh,
    float* __restrict__ sWp)
{
    int w = threadIdx.x >> 6, l = threadIdx.x & 63;
    int wave_id = blockIdx.x * 4 + w;   // 0..255
    float se[4];
    #pragma unroll
    for (int j = 0; j < 4; ++j) {
        float a = 0.f;
        for (int i = 0; i < FEW; ++i) a += sup_ln[i * DMODEL + l + 64 * j];
        se[j] = a * (1.f / FEW);
    }
    for (int i = 0; i < 4; ++i) {
        int p = wave_id * 4 + i;        // 0..1023
        int pp = p >> 8, q = p & 255;
        const float* wr = W_hh + (size_t)(pp * 512 + q) * HIDN + 256;
        float part = 0.f;
        #pragma unroll
        for (int j = 0; j < 4; ++j) part += se[j] * wr[l + 64 * j];
        for (int off = 32; off; off >>= 1) part += __shfl_xor(part, off, 64);
        if (l == 0) sWp[p] = part;
    }
}

// ---------------------------------------------------------------------------
// Kernel 4: fused LSTM (4 steps) + final dot, MFMA 16x16x32 bf16.
// Block = 16 samples, 512 threads (8 waves); wave w owns gate columns
// q in [w*32, w*32+32): n-tiles tp = pp*16 + 2w + qt, qt in {0,1}.
// base gates in registers (MFMA C-init); c in registers; h through LDS.
// ---------------------------------------------------------------------------
__global__ __launch_bounds__(512) void lstm_mfma_kernel(
    const float* __restrict__ query_g, const float* __restrict__ sup_ln,
    const float* __restrict__ sWp, const u16* __restrict__ wih_bf,
    const u16* __restrict__ whh_bf, const float* __restrict__ b_ih,
    const float* __restrict__ b_hh, float* __restrict__ out)
{
    __shared__ __align__(16) float qs[16][260];
    __shared__ __align__(16) float hs[16][260];
    __shared__ float sv[DMODEL];
    int t = threadIdx.x;
    int w = t >> 6, l = t & 63;
    int n0 = blockIdx.x * 16;

    if (t < DMODEL) {
        float a = 0.f;
        for (int i = 0; i < FEW; ++i) a += sup_ln[i * DMODEL + t];
        sv[t] = a * (1.f / FEW);
    }
    #pragma unroll
    for (int j = 0; j < 8; ++j) {
        int idx = j * 512 + t;
        int r = idx >> 8, cc = idx & 255;
        qs[r][cc] = query_g[(size_t)(n0 + r) * DMODEL + cc];
    }
    __syncthreads();

    int am = l & 15, ak = (l >> 4) * 8;

    // A-frags from query
    s16x8 af[8];
    #pragma unroll
    for (int ks = 0; ks < 8; ++ks) {
        float4 x0 = *(const float4*)&qs[am][ks * 32 + ak];
        float4 x1 = *(const float4*)&qs[am][ks * 32 + ak + 4];
        af[ks] = pack8(x0, x1);
    }

    // base GEMM: query @ W_ih_live^T
    f32x4 base[4][2];
    #pragma unroll
    for (int pp = 0; pp < 4; ++pp) {
        #pragma unroll
        for (int qt = 0; qt < 2; ++qt) {
            int tp = pp * 16 + 2 * w + qt;
            f32x4 acc = {0.f, 0.f, 0.f, 0.f};
            const u16* bp = wih_bf + (size_t)tp * 4096 + l * 8;
            #pragma unroll
            for (int ks = 0; ks < 8; ++ks) {
                s16x8 bf = *(const s16x8*)(bp + ks * 512);
                acc = __builtin_amdgcn_mfma_f32_16x16x32_bf16(af[ks], bf, acc, 0, 0, 0);
            }
            base[pp][qt] = acc;
        }
    }
    // + biases
    #pragma unroll
    for (int pp = 0; pp < 4; ++pp) {
        #pragma unroll
        for (int qt = 0; qt < 2; ++qt) {
            int q = w * 32 + qt * 16 + (l & 15);
            float bsv = b_ih[pp * 512 + q] + b_hh[pp * 512 + q];
            base[pp][qt].x += bsv; base[pp][qt].y += bsv;
            base[pp][qt].z += bsv; base[pp][qt].w += bsv;
        }
    }

    // step 0 (h_r = 0, c = 0)
    float c[2][4];
    #pragma unroll
    for (int qt = 0; qt < 2; ++qt) {
        int q = w * 32 + qt * 16 + (l & 15);
        #pragma unroll
        for (int reg = 0; reg < 4; ++reg) {
            int m = (l >> 4) * 4 + reg;
            float gi = base[0][qt][reg];
            float gg = base[2][qt][reg];
            float go = base[3][qt][reg];
            float cc = sigmoidf_(gi) * tanhf(gg);
            c[qt][reg] = cc;
            hs[m][q] = qs[m][q] + sigmoidf_(go) * tanhf(cc);
        }
    }
    // fold sWp into base (steps 1..3 only)
    #pragma unroll
    for (int pp = 0; pp < 4; ++pp) {
        #pragma unroll
        for (int qt = 0; qt < 2; ++qt) {
            int q = w * 32 + qt * 16 + (l & 15);
            float sw = sWp[pp * 256 + q];
            base[pp][qt].x += sw; base[pp][qt].y += sw;
            base[pp][qt].z += sw; base[pp][qt].w += sw;
        }
    }
    __syncthreads();

    // steps 1..3
    for (int st = 1; st < 4; ++st) {
        #pragma unroll
        for (int ks = 0; ks < 8; ++ks) {
            float4 x0 = *(const float4*)&hs[am][ks * 32 + ak];
            float4 x1 = *(const float4*)&hs[am][ks * 32 + ak + 4];
            af[ks] = pack8(x0, x1);
        }
        __syncthreads();   // reads done before epilogue writes

        f32x4 gacc[4][2];
        #pragma unroll
        for (int pp = 0; pp < 4; ++pp) {
            #pragma unroll
            for (int qt = 0; qt < 2; ++qt) {
                int tp = pp * 16 + 2 * w + qt;
                f32x4 acc = base[pp][qt];
                const u16* bp = whh_bf + (size_t)tp * 4096 + l * 8;
                #pragma unroll
                for (int ks = 0; ks < 8; ++ks) {
                    s16x8 bf = *(const s16x8*)(bp + ks * 512);
                    acc = __builtin_amdgcn_mfma_f32_16x16x32_bf16(af[ks], bf, acc, 0, 0, 0);
                }
                gacc[pp][qt] = acc;
            }
        }
        #pragma unroll
        for (int qt = 0; qt < 2; ++qt) {
            int q = w * 32 + qt * 16 + (l & 15);
            #pragma unroll
            for (int reg = 0; reg < 4; ++reg) {
                int m = (l >> 4) * 4 + reg;
                float gi = gacc[0][qt][reg];
                float gf = gacc[1][qt][reg];
                float gg = gacc[2][qt][reg];
                float go = gacc[3][qt][reg];
                float cc = sigmoidf_(gf) * c[qt][reg] + sigmoidf_(gi) * tanhf(gg);
                c[qt][reg] = cc;
                hs[m][q] = qs[m][q] + sigmoidf_(go) * tanhf(cc);
            }
        }
        __syncthreads();
    }

    // final: wave w handles samples 2w, 2w+1
    for (int j = 0; j < 2; ++j) {
        int m = w * 2 + j;
        float part = 0.f;
        #pragma unroll
        for (int i = 0; i < 4; ++i) {
            int e = l + 64 * i;
            part += hs[m][e] * sv[e];
        }
        for (int off = 32; off; off >>= 1) part += __shfl_xor(part, off, 64);
        if (l == 0) out[n0 + m] = part;
    }
}

// ---------------------------------------------------------------------------
extern "C" void kernel_launch(void* const* d_in, const int* in_sizes, int n_in,
                              void* d_out, int out_size, void* d_ws, size_t ws_size,
                              hipStream_t stream)
{
    const int*   qlc  = (const int*)d_in[0];
    const int*   qrc  = (const int*)d_in[1];
    const int*   slc  = (const int*)d_in[2];
    const int*   src_ = (const int*)d_in[3];
    // d_in[4..7]: degrees — unused by the reference
    const float* emb   = (const float*)d_in[8];
    const float* gcnW  = (const float*)d_in[9];
    const float* gcnwb = (const float*)d_in[10];
    const float* gcnb  = (const float*)d_in[11];
    const float* p1W   = (const float*)d_in[12];
    const float* p1b   = (const float*)d_in[13];
    const float* p2W   = (const float*)d_in[14];
    const float* p2b   = (const float*)d_in[15];
    const float* lng   = (const float*)d_in[16];
    const float* lnb   = (const float*)d_in[17];
    const float* W_ih  = (const float*)d_in[18];
    const float* W_hh  = (const float*)d_in[19];
    const float* b_ih  = (const float*)d_in[20];
    const float* b_hh  = (const float*)d_in[21];
    float* out = (float*)d_out;

    // Workspace layout
    char* ws = (char*)d_ws;
    float* qn      = (float*)(ws + 0);         // 1048576
    float* sn      = (float*)(ws + 1048576);   // 5120
    float* query_g = (float*)(ws + 1053696);   // 1048576
    float* sup_ln  = (float*)(ws + 2102272);   // 5120
    float* sWp     = (float*)(ws + 2107392);   // 4096
    u16*   wih_bf  = (u16*)(ws + 2111488);     // 524288
    u16*   whh_bf  = (u16*)(ws + 2635776);     // 524288
    u16*   p1_bf   = (u16*)(ws + 3160064);     // 262144
    u16*   p2_bf   = (u16*)(ws + 3422208);     // 262144
    u16*   emb_bf  = (u16*)(ws + 3684352);     // 51200256 -> total 54884608
    (void)in_sizes; (void)n_in; (void)out_size;

    bool have_emb = ws_size >= (size_t)3684352 + (size_t)EMB_ELEMS * 2;
    int grid_conv = 384 + (have_emb ? EMB_BLOCKS : 0);

    convert_all_kernel<<<grid_conv, 256, 0, stream>>>(
        W_ih, W_hh, p1W, p2W, emb, wih_bf, whh_bf, p1_bf, p2_bf, emb_bf);
    if (have_emb)
        neighbor_kernel<true><<<2 * BQ + 2 * FEW, 256, 0, stream>>>(
            qlc, qrc, slc, src_, emb, emb_bf, gcnW, gcnwb, gcnb, qn, sn);
    else
        neighbor_kernel<false><<<2 * BQ + 2 * FEW, 256, 0, stream>>>(
            qlc, qrc, slc, src_, emb, emb_bf, gcnW, gcnwb, gcnb, qn, sn);
    support_enc_kernel<<<(BQ + FEW + 15) / 16, 512, 0, stream>>>(
        qn, sn, p1_bf, p1b, p2_bf, p2b, lng, lnb, query_g, sup_ln);
    sWp_kernel<<<64, 256, 0, stream>>>(sup_ln, W_hh, sWp);
    lstm_mfma_kernel<<<BQ / 16, 512, 0, stream>>>(
        query_g, sup_ln, sWp, wih_bf, whh_bf, b_ih, b_hh, out);
}